// Round 1
// 2685.892 us; speedup vs baseline: 1.2510x; 1.2510x over previous
//
#include <hip/hip_runtime.h>

#define LDSW 40
#define SCAN_P 128
#define SCAN_L 64

typedef short short8 __attribute__((ext_vector_type(8)));
typedef float floatx4 __attribute__((ext_vector_type(4)));
typedef unsigned short u16;

__device__ __forceinline__ u16 bf16_rne(float v) {
    unsigned int u = __float_as_uint(v);
    u = u + 0x7fffu + ((u >> 16) & 1u);
    return (u16)(u >> 16);
}
__device__ __forceinline__ float bf16_to_f(u16 h) {
    return __uint_as_float(((unsigned int)h) << 16);
}
__device__ __forceinline__ float sigm(float x) { return 1.f / (1.f + expf(-x)); }
__device__ __forceinline__ float logsig(float x) {
    const float l = log1pf(expf(-fabsf(x)));
    return x >= 0.f ? -l : x - l;
}

// fp32 -> bf16 hi/lo split of 8 contiguous elements
__device__ __forceinline__ void cvt8(const float* p, short8& h8, short8& l8) {
    const float4 a = *(const float4*)p;
    const float4 b = *(const float4*)(p + 4);
    const float v[8] = {a.x, a.y, a.z, a.w, b.x, b.y, b.z, b.w};
#pragma unroll
    for (int j = 0; j < 8; ++j) {
        const u16 hh = bf16_rne(v[j]);
        h8[j] = (short)hh;
        l8[j] = (short)bf16_rne(v[j] - bf16_to_f(hh));
    }
}
__device__ __forceinline__ void cvt8h(const float* p, short8& h8) {
    const float4 a = *(const float4*)p;
    const float4 b = *(const float4*)(p + 4);
    const float v[8] = {a.x, a.y, a.z, a.w, b.x, b.y, b.z, b.w};
#pragma unroll
    for (int j = 0; j < 8; ++j) h8[j] = (short)bf16_rne(v[j]);
}

// async global -> LDS, 16B per lane, wave-uniform LDS base (HW adds lane*16)
__device__ __forceinline__ void gld16(const u16* g, u16* l) {
    __builtin_amdgcn_global_load_lds(
        (const __attribute__((address_space(1))) void*)g,
        (__attribute__((address_space(3))) void*)l, 16, 0, 0);
}

// ---------------------------------------------------------------------------
// OLD kernel (kept verbatim for the small-workspace fallback path B).
// ---------------------------------------------------------------------------
template <int AFMT, int NPROD, int EPI, int ACC, int ST>
__global__ __launch_bounds__(256, 2) void gemm_f32(
    const float* __restrict__ Af, const u16* __restrict__ Au,
    const float* __restrict__ Bf, const float* __restrict__ bias,
    float* C, u16* Chi, u16* Clo, const float* Q,
    long ldA, long ldB, long ldC, int K)
{
    __shared__ __align__(16) u16 sAh[128 * LDSW];
    __shared__ __align__(16) u16 sBh[128 * LDSW];
    __shared__ __align__(16) u16 sAl[NPROD == 3 ? 128 * LDSW : 8];
    __shared__ __align__(16) u16 sBl[NPROD == 3 ? 128 * LDSW : 8];

    const int tid  = threadIdx.x;
    const int lane = tid & 63;
    const int wid  = tid >> 6;
    const int wm   = (wid >> 1) << 6;
    const int wn   = (wid & 1) << 6;
    const int m16  = lane & 15;
    const int kq   = lane >> 4;
    const int koff = kq << 3;
    const long bM  = (long)blockIdx.y << 7;
    const long bN  = (long)blockIdx.x << 7;
    const int sr   = tid >> 2;
    const int sc   = (tid & 3) << 3;

    floatx4 acc[4][4] = {};

#pragma unroll 1
    for (int k0 = 0; k0 < K; k0 += 32) {
        __syncthreads();
#pragma unroll
        for (int i = 0; i < 2; ++i) {
            const int r  = sr + (i << 6);
            const int ls = r * LDSW + sc;
            if constexpr (AFMT == 0) {
                if constexpr (NPROD == 3) {
                    short8 h8, l8;
                    cvt8(Af + (bM + r) * ldA + k0 + sc, h8, l8);
                    *(short8*)&sAh[ls] = h8;
                    *(short8*)&sAl[ls] = l8;
                } else {
                    short8 h8;
                    cvt8h(Af + (bM + r) * ldA + k0 + sc, h8);
                    *(short8*)&sAh[ls] = h8;
                }
            } else {
                *(short8*)&sAh[ls] = *(const short8*)(Au + (bM + r) * ldA + k0 + sc);
            }
            if constexpr (NPROD == 3) {
                short8 h8, l8;
                cvt8(Bf + (bN + r) * ldB + k0 + sc, h8, l8);
                *(short8*)&sBh[ls] = h8;
                *(short8*)&sBl[ls] = l8;
            } else {
                short8 h8;
                cvt8h(Bf + (bN + r) * ldB + k0 + sc, h8);
                *(short8*)&sBh[ls] = h8;
            }
        }
        __syncthreads();

        short8 ah[4], bh[4];
#pragma unroll
        for (int t = 0; t < 4; ++t) {
            ah[t] = *(const short8*)&sAh[(wm + t * 16 + m16) * LDSW + koff];
            bh[t] = *(const short8*)&sBh[(wn + t * 16 + m16) * LDSW + koff];
        }
#pragma unroll
        for (int mi = 0; mi < 4; ++mi)
#pragma unroll
            for (int ni = 0; ni < 4; ++ni)
                acc[mi][ni] = __builtin_amdgcn_mfma_f32_16x16x32_bf16(ah[mi], bh[ni], acc[mi][ni], 0, 0, 0);

        if constexpr (NPROD == 3) {
            short8 al[4], bl[4];
#pragma unroll
            for (int t = 0; t < 4; ++t) {
                al[t] = *(const short8*)&sAl[(wm + t * 16 + m16) * LDSW + koff];
                bl[t] = *(const short8*)&sBl[(wn + t * 16 + m16) * LDSW + koff];
            }
#pragma unroll
            for (int mi = 0; mi < 4; ++mi)
#pragma unroll
                for (int ni = 0; ni < 4; ++ni)
                    acc[mi][ni] = __builtin_amdgcn_mfma_f32_16x16x32_bf16(ah[mi], bl[ni], acc[mi][ni], 0, 0, 0);
#pragma unroll
            for (int mi = 0; mi < 4; ++mi)
#pragma unroll
                for (int ni = 0; ni < 4; ++ni)
                    acc[mi][ni] = __builtin_amdgcn_mfma_f32_16x16x32_bf16(al[mi], bh[ni], acc[mi][ni], 0, 0, 0);
        }
    }

    float bv[4];
#pragma unroll
    for (int ni = 0; ni < 4; ++ni) bv[ni] = bias ? bias[bN + wn + ni * 16 + m16] : 0.f;

#pragma unroll
    for (int mi = 0; mi < 4; ++mi) {
#pragma unroll
        for (int ni = 0; ni < 4; ++ni) {
#pragma unroll
            for (int r = 0; r < 4; ++r) {
                const long grow = bM + wm + mi * 16 + (kq << 2) + r;
                const long gcol = bN + wn + ni * 16 + m16;
                const long idx  = grow * ldC + gcol;
                float v = acc[mi][ni][r] + bv[ni];
                if constexpr (ACC) v += C[idx];
                if constexpr (EPI == 1) v *= Q[idx];
                if constexpr (EPI == 2)
                    v = 0.5f * v * (1.f + tanhf(0.7978845608028654f * (v + 0.044715f * v * v * v)));
                if constexpr (ST == 1) {
                    const u16 h = bf16_rne(v);
                    Chi[idx] = h;
                    Clo[idx] = bf16_rne(v - bf16_to_f(h));
                } else {
                    C[idx] = v;
                }
            }
        }
    }
}

// ---------------------------------------------------------------------------
// NEW GEMM: operands pre-split to bf16 hi/lo u16 planes in HBM, staged with
// global_load_lds dwordx4 (no VALU cvt in the hot loop).  LDS tile is
// [128 rows][32 u16] linear (DMA-compatible) with an XOR chunk swizzle:
// physical 16B-chunk = logical ^ ((row>>1)&3), applied identically to the
// DMA *source* address and the ds_read address (both-sides rule) -> 2-way
// bank aliasing on ds_read_b128 (free per m136).
//   NPROD=3: AhBh+AhBl+AlBh.  BFMT=0: B is fp32, cvt in-kernel (phase-1
//   weights; workspace-bound).  EPI: 0 none, 1 v*=Q[idx], 2 gelu,
//   3 v=exp(8*sigm(v)*logsig(vvec[col])) [a], 4 v=sqrt(1-Q[idx]^2)*sigm(v)
//   [q].  ACC: C+=.  ST=1: store bf16-hi only to Chi.  DOT=1: fuse
//   zb2[row] += sum_col v*vvec[col] (exact fp32, shuffle-reduced, atomic).
// ---------------------------------------------------------------------------
template <int NPROD, int BFMT, int EPI, int ACC, int ST, int DOT>
__global__ __launch_bounds__(256, 2) void gemm_sp(
    const u16* __restrict__ Ah, const u16* __restrict__ Al,
    const u16* __restrict__ Bh, const u16* __restrict__ Bl,
    const float* __restrict__ Bf, const float* __restrict__ bias,
    float* C, u16* Chi, const float* Q,
    const float* __restrict__ vvec, float* dacc,
    long ldA, long ldB, long ldC, int K)
{
    __shared__ __align__(16) u16 sAh[128 * 32];
    __shared__ __align__(16) u16 sBh[128 * 32];
    __shared__ __align__(16) u16 sAl[NPROD == 3 ? 128 * 32 : 8];
    __shared__ __align__(16) u16 sBl[NPROD == 3 ? 128 * 32 : 8];

    const int tid  = threadIdx.x;
    const int lane = tid & 63;
    const int wid  = tid >> 6;
    const int wm   = (wid >> 1) << 6;
    const int wn   = (wid & 1) << 6;
    const int m16  = lane & 15;
    const int kq   = lane >> 4;
    const long bM  = (long)blockIdx.y << 7;
    const long bN  = (long)blockIdx.x << 7;

    // DMA staging: wave wid stages relative rows [wid*32, wid*32+32), two
    // 1024B instructions (j=0,1) per plane.  Lane l carries (row base+l/4,
    // physical chunk l&3); source logical chunk = (l&3) ^ ((l>>3)&3).
    const int  drow = (wid << 5) + (lane >> 2);
    const int  qsrc = (((lane & 3) ^ ((lane >> 3) & 3)) << 3);
    const long a0   = (bM + drow) * ldA + qsrc;
    const long a1   = a0 + 16 * ldA;
    const long b0   = (bN + drow) * ldB + qsrc;
    const long b1   = b0 + 16 * ldB;
    u16* const lA0  = &sAh[(wid << 5) << 5];
    u16* const lA1  = lA0 + 512;
    u16* const lB0  = &sBh[(wid << 5) << 5];
    u16* const lB1  = lB0 + 512;
    u16* const lAl0 = &sAl[NPROD == 3 ? ((wid << 5) << 5) : 0];
    u16* const lAl1 = lAl0 + (NPROD == 3 ? 512 : 0);
    u16* const lBl0 = &sBl[NPROD == 3 ? ((wid << 5) << 5) : 0];
    u16* const lBl1 = lBl0 + (NPROD == 3 ? 512 : 0);

    // reg-staging geometry for BFMT==0 (B fp32 cvt) — same swizzle on write
    const int sr  = tid >> 2;
    const int sc  = (tid & 3) << 3;
    const int wch = (((tid & 3) ^ ((sr >> 1) & 3)) << 3);

    // fragment-read physical chunk: kq ^ ((row>>1)&3) == kq ^ ((m16>>1)&3)
    const int kr = ((kq ^ ((m16 >> 1) & 3)) << 3);

    floatx4 acc[4][4] = {};

#pragma unroll 1
    for (int k0 = 0; k0 < K; k0 += 32) {
        __syncthreads();
        gld16(Ah + a0 + k0, lA0);
        gld16(Ah + a1 + k0, lA1);
        if constexpr (NPROD == 3) {
            gld16(Al + a0 + k0, lAl0);
            gld16(Al + a1 + k0, lAl1);
        }
        if constexpr (BFMT == 1) {
            gld16(Bh + b0 + k0, lB0);
            gld16(Bh + b1 + k0, lB1);
            if constexpr (NPROD == 3) {
                gld16(Bl + b0 + k0, lBl0);
                gld16(Bl + b1 + k0, lBl1);
            }
        } else {
#pragma unroll
            for (int i = 0; i < 2; ++i) {
                const int r = sr + (i << 6);
                short8 h8, l8;
                cvt8(Bf + (bN + r) * ldB + k0 + sc, h8, l8);
                *(short8*)&sBh[(r << 5) + wch] = h8;
                *(short8*)&sBl[(r << 5) + wch] = l8;
            }
        }
        __syncthreads();

        short8 ah[4], bh[4];
#pragma unroll
        for (int t = 0; t < 4; ++t) {
            ah[t] = *(const short8*)&sAh[((wm + t * 16 + m16) << 5) + kr];
            bh[t] = *(const short8*)&sBh[((wn + t * 16 + m16) << 5) + kr];
        }
#pragma unroll
        for (int mi = 0; mi < 4; ++mi)
#pragma unroll
            for (int ni = 0; ni < 4; ++ni)
                acc[mi][ni] = __builtin_amdgcn_mfma_f32_16x16x32_bf16(ah[mi], bh[ni], acc[mi][ni], 0, 0, 0);

        if constexpr (NPROD == 3) {
            short8 al[4], bl[4];
#pragma unroll
            for (int t = 0; t < 4; ++t) {
                al[t] = *(const short8*)&sAl[((wm + t * 16 + m16) << 5) + kr];
                bl[t] = *(const short8*)&sBl[((wn + t * 16 + m16) << 5) + kr];
            }
#pragma unroll
            for (int mi = 0; mi < 4; ++mi)
#pragma unroll
                for (int ni = 0; ni < 4; ++ni)
                    acc[mi][ni] = __builtin_amdgcn_mfma_f32_16x16x32_bf16(ah[mi], bl[ni], acc[mi][ni], 0, 0, 0);
#pragma unroll
            for (int mi = 0; mi < 4; ++mi)
#pragma unroll
                for (int ni = 0; ni < 4; ++ni)
                    acc[mi][ni] = __builtin_amdgcn_mfma_f32_16x16x32_bf16(al[mi], bh[ni], acc[mi][ni], 0, 0, 0);
        }
    }

    float bv[4];
#pragma unroll
    for (int ni = 0; ni < 4; ++ni) bv[ni] = bias ? bias[bN + wn + ni * 16 + m16] : 0.f;
    float vv[4] = {}, ls[4] = {};
    if constexpr (EPI == 3 || DOT == 1) {
#pragma unroll
        for (int ni = 0; ni < 4; ++ni) {
            vv[ni] = vvec[bN + wn + ni * 16 + m16];
            if constexpr (EPI == 3) ls[ni] = logsig(vv[ni]);
        }
    }
    float ds[4][4] = {};

#pragma unroll
    for (int mi = 0; mi < 4; ++mi) {
#pragma unroll
        for (int ni = 0; ni < 4; ++ni) {
#pragma unroll
            for (int r = 0; r < 4; ++r) {
                // C/D: col = lane&15, row = (lane>>4)*4 + reg  [m89-verified]
                const long grow = bM + wm + mi * 16 + (kq << 2) + r;
                const long gcol = bN + wn + ni * 16 + m16;
                const long idx  = grow * ldC + gcol;
                float v = acc[mi][ni][r] + bv[ni];
                if constexpr (EPI == 1) v *= Q[idx];
                if constexpr (EPI == 2)
                    v = 0.5f * v * (1.f + tanhf(0.7978845608028654f * (v + 0.044715f * v * v * v)));
                if constexpr (EPI == 3) v = expf(8.f * sigm(v) * ls[ni]);
                if constexpr (EPI == 4) {
                    const float a = Q[idx];
                    v = sqrtf(fmaxf(1.f - a * a, 0.f)) * sigm(v);
                }
                if constexpr (ACC) v += C[idx];
                if constexpr (DOT) ds[mi][r] += v * vv[ni];
                if constexpr (ST == 1) Chi[idx] = bf16_rne(v);
                else C[idx] = v;
            }
        }
    }

    if constexpr (DOT) {
#pragma unroll
        for (int mi = 0; mi < 4; ++mi)
#pragma unroll
            for (int r = 0; r < 4; ++r) {
                float s = ds[mi][r];
                s += __shfl_xor(s, 1);
                s += __shfl_xor(s, 2);
                s += __shfl_xor(s, 4);
                s += __shfl_xor(s, 8);
                if (m16 == 0)
                    atomicAdd(&dacc[bM + wm + mi * 16 + (kq << 2) + r], s);
            }
    }
}

// ---------------------------------------------------------------------------
// fp32 -> bf16 hi(/lo) planes.  One block per row, 2048 cols.
template <int HASLO>
__global__ __launch_bounds__(256) void split_kernel(
    const float* __restrict__ src, long lds,
    u16* __restrict__ hi, u16* __restrict__ lo, long ldd)
{
    const long r = blockIdx.x;
    const int  c = threadIdx.x << 3;
    const float* p = src + r * lds + c;
    const float4 a = *(const float4*)p;
    const float4 b = *(const float4*)(p + 4);
    const float v[8] = {a.x, a.y, a.z, a.w, b.x, b.y, b.z, b.w};
    short8 h8, l8;
#pragma unroll
    for (int j = 0; j < 8; ++j) {
        const u16 hh = bf16_rne(v[j]);
        h8[j] = (short)hh;
        if constexpr (HASLO) l8[j] = (short)bf16_rne(v[j] - bf16_to_f(hh));
    }
    *(short8*)&hi[r * ldd + c] = h8;
    if constexpr (HASLO) *(short8*)&lo[r * ldd + c] = l8;
}

__global__ __launch_bounds__(256) void zb2init_kernel(
    float* __restrict__ zb2, const float* __restrict__ zc2)
{
    zb2[blockIdx.x * 256 + threadIdx.x] = zc2[0];
}

// ---------------------------------------------------------------------------
// za(slabA), zg(d_out) -> a(slabA), q=sqrt(1-exp(2 log_a))*g (d_out), in place
// (fallback path B only)
__global__ __launch_bounds__(256) void aq_kernel(
    float* za, float* zg, const float* __restrict__ lam)
{
    const long i = ((long)blockIdx.x * 256 + threadIdx.x) * 4;
    const int  c = (int)(i & 2047);
    const float4 zav = *(const float4*)(za + i);
    const float4 zgv = *(const float4*)(zg + i);
    const float4 lmv = *(const float4*)(lam + c);
    float4 av, qv;
    const float zaa[4] = {zav.x, zav.y, zav.z, zav.w};
    const float zga[4] = {zgv.x, zgv.y, zgv.z, zgv.w};
    const float lma[4] = {lmv.x, lmv.y, lmv.z, lmv.w};
    float aa[4], qa[4];
#pragma unroll
    for (int j = 0; j < 4; ++j) {
        const float r  = sigm(zaa[j]);
        const float g  = sigm(zga[j]);
        const float la = 8.f * r * logsig(lma[j]);
        aa[j] = expf(la);
        qa[j] = sqrtf(fmaxf(1.f - expf(2.f * la), 0.f)) * g;
    }
    av.x = aa[0]; av.y = aa[1]; av.z = aa[2]; av.w = aa[3];
    qv.x = qa[0]; qv.y = qa[1]; qv.z = qa[2]; qv.w = qa[3];
    *(float4*)(za + i) = av;
    *(float4*)(zg + i) = qv;
}

// ---------------------------------------------------------------------------
// chunked scan over S (stride 2048): h_t = a_t h_{t-1} + b_t
__global__ __launch_bounds__(256) void scan_partial(
    const float* __restrict__ A, const float* __restrict__ B,
    float* __restrict__ Aagg, float* __restrict__ Bagg)
{
    const int c = blockIdx.x * 256 + threadIdx.x;
    const int p = blockIdx.y;
    const long base = (long)p * SCAN_L * 2048 + c;
    float Ar = 1.f, Br = 0.f;
    for (int t = 0; t < SCAN_L; ++t) {
        const float at = A[base + (long)t * 2048];
        const float bt = B[base + (long)t * 2048];
        Ar *= at;
        Br = Br * at + bt;
    }
    Aagg[p * 2048 + c] = Ar;
    Bagg[p * 2048 + c] = Br;
}

__global__ __launch_bounds__(256) void scan_combine(
    const float* __restrict__ Aagg, const float* __restrict__ Bagg,
    float* __restrict__ Hini)
{
    const int c = blockIdx.x * 256 + threadIdx.x;
    float h = 0.f;
    for (int p = 0; p < SCAN_P; ++p) {
        Hini[p * 2048 + c] = h;
        h = Aagg[p * 2048 + c] * h + Bagg[p * 2048 + c];
    }
}

__global__ __launch_bounds__(256) void scan_final(
    float* A, const float* __restrict__ B, const float* __restrict__ Hini)
{
    const int c = blockIdx.x * 256 + threadIdx.x;
    const int p = blockIdx.y;
    const long base = (long)p * SCAN_L * 2048 + c;
    float h = Hini[p * 2048 + c];
    for (int t = 0; t < SCAN_L; ++t) {
        const long idx = base + (long)t * 2048;
        h = A[idx] * h + B[idx];
        A[idx] = h;
    }
}

// ---------------------------------------------------------------------------
// v[j] = sum_d W[d,j] * w[d]   (chunked partials, then reduce)
__global__ __launch_bounds__(256) void vpart_kernel(
    const float* __restrict__ W, const float* __restrict__ w,
    float* __restrict__ part, long ldW, int dchunk)
{
    const int j  = blockIdx.x * 256 + threadIdx.x;
    const int d0 = blockIdx.y * dchunk;
    float s = 0.f;
    for (int d = 0; d < dchunk; ++d) s += W[(long)(d0 + d) * ldW + j] * w[d0 + d];
    part[(long)blockIdx.y * ldW + j] = s;
}

__global__ __launch_bounds__(256) void vreduce_kernel(
    const float* __restrict__ part, float* __restrict__ v, long ldW, int nch)
{
    const int j = blockIdx.x * 256 + threadIdx.x;
    float s = 0.f;
    for (int c = 0; c < nch; ++c) s += part[(long)c * ldW + j];
    v[j] = s;
}

__global__ __launch_bounds__(256) void dotc_kernel(
    const float* __restrict__ a, const float* __restrict__ b,
    const float* __restrict__ bias1, float* __restrict__ out)
{
    __shared__ float red[4];
    const int tid = threadIdx.x, lane = tid & 63, wid = tid >> 6;
    float s = 0.f;
    for (int d = tid; d < 2048; d += 256) s += a[d] * b[d];
#pragma unroll
    for (int off = 32; off > 0; off >>= 1) s += __shfl_down(s, off);
    if (lane == 0) red[wid] = s;
    __syncthreads();
    if (tid == 0) out[0] = red[0] + red[1] + red[2] + red[3] + bias1[0];
}

// ---------------------------------------------------------------------------
// zb[s] (+)= sum_{f<L} (uHi+uLo)[s,f] * v2s[f]  (+ zc on INIT)  (path B only)
template <int INIT>
__global__ __launch_bounds__(256) void zacc_kernel(
    const u16* __restrict__ uHi, const u16* __restrict__ uLo,
    const float* __restrict__ v2s, const float* __restrict__ zc,
    float* __restrict__ zb, int L)
{
    __shared__ float red[4];
    const int tid = threadIdx.x, lane = tid & 63, wid = tid >> 6;
    const long s = blockIdx.x;
    const long base = s * (long)L;
    float dot = 0.f;
    for (int f = tid; f < L; f += 256)
        dot += (bf16_to_f(uHi[base + f]) + bf16_to_f(uLo[base + f])) * v2s[f];
#pragma unroll
    for (int off = 32; off > 0; off >>= 1) dot += __shfl_down(dot, off);
    if (lane == 0) red[wid] = dot;
    __syncthreads();
    if (tid == 0) {
        const float t = red[0] + red[1] + red[2] + red[3];
        zb[s] = INIT ? (zc[0] + t) : (zb[s] + t);
    }
}

// ---------------------------------------------------------------------------
// gate1 (path B): fp32 x1 in place over res1
__global__ __launch_bounds__(256) void gate1_kernel(
    const float* __restrict__ x, float* res1x1,
    const float* __restrict__ h,
    const float* __restrict__ v1, const float* __restrict__ zc1,
    const float* __restrict__ u1,
    const float* __restrict__ nw, const float* __restrict__ nb)
{
    __shared__ float red[4];
    const int tid = threadIdx.x, lane = tid & 63, wid = tid >> 6;
    const long s = blockIdx.x;
    const long base = s * 2048;

    float dot = 0.f;
#pragma unroll
    for (int k = 0; k < 8; ++k) {
        const int d = tid + (k << 8);
        dot += h[base + d] * v1[d];
    }
#pragma unroll
    for (int off = 32; off > 0; off >>= 1) dot += __shfl_down(dot, off);
    if (lane == 0) red[wid] = dot;
    __syncthreads();
    const float z = red[0] + red[1] + red[2] + red[3] + zc1[0];
    __syncthreads();

    const float g = (u1[s] < sigm(z)) ? 1.f : 0.f;

    float yv[8];
    float ss = 0.f;
#pragma unroll
    for (int k = 0; k < 8; ++k) {
        const int d = tid + (k << 8);
        const float y = x[base + d] + g * res1x1[base + d];
        yv[k] = y;
        ss += y * y;
    }
#pragma unroll
    for (int off = 32; off > 0; off >>= 1) ss += __shfl_down(ss, off);
    if (lane == 0) red[wid] = ss;
    __syncthreads();
    const float inv = rsqrtf((red[0] + red[1] + red[2] + red[3]) * (1.f / 2048.f) + 1e-6f);

#pragma unroll
    for (int k = 0; k < 8; ++k) {
        const int d = tid + (k << 8);
        res1x1[base + d] = yv[k] * inv * nw[d] + nb[d];
    }
}

// gate1 (path A): writes x1 as row-interleaved bf16 hi/lo split, in place
// over res1 (row s: u16[s*4096 + d] = hi, u16[s*4096 + 2048 + d] = lo).
// All res1 reads happen before the reduction barrier; writes after it.
__global__ __launch_bounds__(256) void gate1s_kernel(
    const float* __restrict__ x, float* res1x1,
    const float* __restrict__ h,
    const float* __restrict__ v1, const float* __restrict__ zc1,
    const float* __restrict__ u1,
    const float* __restrict__ nw, const float* __restrict__ nb)
{
    __shared__ float red[4];
    const int tid = threadIdx.x, lane = tid & 63, wid = tid >> 6;
    const long s = blockIdx.x;
    const long base = s * 2048;

    float dot = 0.f;
#pragma unroll
    for (int k = 0; k < 8; ++k) {
        const int d = tid + (k << 8);
        dot += h[base + d] * v1[d];
    }
#pragma unroll
    for (int off = 32; off > 0; off >>= 1) dot += __shfl_down(dot, off);
    if (lane == 0) red[wid] = dot;
    __syncthreads();
    const float z = red[0] + red[1] + red[2] + red[3] + zc1[0];
    __syncthreads();

    const float g = (u1[s] < sigm(z)) ? 1.f : 0.f;

    float yv[8];
    float ss = 0.f;
#pragma unroll
    for (int k = 0; k < 8; ++k) {
        const int d = tid + (k << 8);
        const float y = x[base + d] + g * res1x1[base + d];
        yv[k] = y;
        ss += y * y;
    }
#pragma unroll
    for (int off = 32; off > 0; off >>= 1) ss += __shfl_down(ss, off);
    if (lane == 0) red[wid] = ss;
    __syncthreads();
    const float inv = rsqrtf((red[0] + red[1] + red[2] + red[3]) * (1.f / 2048.f) + 1e-6f);

    u16* xs = (u16*)res1x1;
    const long sb = s * 4096;
#pragma unroll
    for (int k = 0; k < 8; ++k) {
        const int d = tid + (k << 8);
        const float o = yv[k] * inv * nw[d] + nb[d];
        const u16 hh = bf16_rne(o);
        xs[sb + d] = hh;
        xs[sb + 2048 + d] = bf16_rne(o - bf16_to_f(hh));
    }
}

// gate2 (path B): fp32 x1 in, fp32 out in place
__global__ __launch_bounds__(256) void gate2_kernel(
    float* x1out, const float* __restrict__ res2,
    const float* __restrict__ zb2, const float* __restrict__ u2,
    const float* __restrict__ nw, const float* __restrict__ nb)
{
    __shared__ float red[4];
    const int tid = threadIdx.x, lane = tid & 63, wid = tid >> 6;
    const long s = blockIdx.x;
    const long base = s * 2048;

    const float g = (u2[s] < sigm(zb2[s])) ? 1.f : 0.f;

    float yv[8];
    float ss = 0.f;
#pragma unroll
    for (int k = 0; k < 8; ++k) {
        const int d = tid + (k << 8);
        const float y = x1out[base + d] + g * res2[base + d];
        yv[k] = y;
        ss += y * y;
    }
#pragma unroll
    for (int off = 32; off > 0; off >>= 1) ss += __shfl_down(ss, off);
    if (lane == 0) red[wid] = ss;
    __syncthreads();
    const float inv = rsqrtf((red[0] + red[1] + red[2] + red[3]) * (1.f / 2048.f) + 1e-6f);

#pragma unroll
    for (int k = 0; k < 8; ++k) {
        const int d = tid + (k << 8);
        x1out[base + d] = yv[k] * inv * nw[d] + nb[d];
    }
}

// gate2 (path A): x1 reconstructed from hi+lo split; fp32 out in place.
__global__ __launch_bounds__(256) void gate2s_kernel(
    float* x1out, const float* __restrict__ res2,
    const float* __restrict__ zb2, const float* __restrict__ u2,
    const float* __restrict__ nw, const float* __restrict__ nb)
{
    __shared__ float red[4];
    const int tid = threadIdx.x, lane = tid & 63, wid = tid >> 6;
    const long s = blockIdx.x;
    const long base = s * 2048;
    const u16* xs = (const u16*)x1out;
    const long sb = s * 4096;

    const float g = (u2[s] < sigm(zb2[s])) ? 1.f : 0.f;

    float yv[8];
    float ss = 0.f;
#pragma unroll
    for (int k = 0; k < 8; ++k) {
        const int d = tid + (k << 8);
        const float x1 = bf16_to_f(xs[sb + d]) + bf16_to_f(xs[sb + 2048 + d]);
        const float y = x1 + g * res2[base + d];
        yv[k] = y;
        ss += y * y;
    }
#pragma unroll
    for (int off = 32; off > 0; off >>= 1) ss += __shfl_down(ss, off);
    if (lane == 0) red[wid] = ss;
    __syncthreads();
    const float inv = rsqrtf((red[0] + red[1] + red[2] + red[3]) * (1.f / 2048.f) + 1e-6f);

#pragma unroll
    for (int k = 0; k < 8; ++k) {
        const int d = tid + (k << 8);
        x1out[base + d] = yv[k] * inv * nw[d] + nb[d];
    }
}

// ---------------------------------------------------------------------------
extern "C" void kernel_launch(void* const* d_in, const int* in_sizes, int n_in,
                              void* d_out, int out_size, void* d_ws, size_t ws_size,
                              hipStream_t stream)
{
    const float* x     = (const float*)d_in[0];
    const float* W_in  = (const float*)d_in[1];
    const float* b_in  = (const float*)d_in[2];
    const float* W_a   = (const float*)d_in[3];
    const float* b_a   = (const float*)d_in[4];
    const float* W_g   = (const float*)d_in[5];
    const float* b_g   = (const float*)d_in[6];
    const float* lam   = (const float*)d_in[7];
    const float* W_out = (const float*)d_in[8];
    const float* b_out = (const float*)d_in[9];
    const float* w1    = (const float*)d_in[10];
    const float* fb1   = (const float*)d_in[11];
    const float* w2    = (const float*)d_in[12];
    const float* fb2   = (const float*)d_in[13];
    const float* a1w   = (const float*)d_in[14];
    const float* a1b   = (const float*)d_in[15];
    const float* a2w   = (const float*)d_in[16];
    const float* a2b   = (const float*)d_in[17];
    const float* n1w   = (const float*)d_in[18];
    const float* n1b   = (const float*)d_in[19];
    const float* n2w   = (const float*)d_in[20];
    const float* n2b   = (const float*)d_in[21];
    const float* u1    = (const float*)d_in[22];
    const float* u2    = (const float*)d_in[23];
    (void)in_sizes; (void)n_in; (void)out_size;

    float* dob = (float*)d_out;          // 64 MiB fp32 scratch until final write

    char* ws = (char*)d_ws;
    size_t o = 0;
    auto take = [&](size_t bytes) -> char* {
        char* p = ws + o;
        o += (bytes + 255) & ~(size_t)255;
        return p;
    };

    float* Aagg = (float*)take((size_t)SCAN_P * 2048 * 4);
    float* Bagg = (float*)take((size_t)SCAN_P * 2048 * 4);
    float* Hini = (float*)take((size_t)SCAN_P * 2048 * 4);
    float* v1   = (float*)take(2048 * 4);
    float* v2   = (float*)take(8192 * 4);
    float* vp   = (float*)take(16 * 8192 * 4);
    float* zc1  = (float*)take(256);
    float* zc2  = (float*)take(256);
    float* zb2  = (float*)take(8192 * 4);

    float* slabA = (float*)take(64ull << 20);
    const bool pathA = ws_size >= o + (64ull << 20);
    float* slabB = nullptr;
    float* res2b = nullptr;
    if (pathA) slabB = (float*)take(64ull << 20);
    else       res2b = (float*)take(16ull << 20);
    if (o > ws_size) return;  // diagnostic: absmax == max|ref| signature

    const dim3 blk(256);

    // gate-logit vectors (exact fp32 path; gates never see GEMM error)
    vpart_kernel<<<dim3(8, 16), blk, 0, stream>>>(W_out, a1w, vp, 2048, 128);
    vreduce_kernel<<<8, blk, 0, stream>>>(vp, v1, 2048, 16);
    vpart_kernel<<<dim3(32, 16), blk, 0, stream>>>(w2, a2w, vp, 8192, 128);
    vreduce_kernel<<<32, blk, 0, stream>>>(vp, v2, 8192, 16);
    dotc_kernel<<<1, blk, 0, stream>>>(b_out, a1w, a1b, zc1);
    dotc_kernel<<<1, blk, 0, stream>>>(fb2, a2w, a2b, zc2);

    if (pathA) {
        // ---- phase 1: pre-split A(x), B weights cvt in-kernel (ws-bound) ----
        u16* const xh = (u16*)slabA;
        u16* const xl = xh + (1u << 24);
        split_kernel<1><<<8192, blk, 0, stream>>>(x, 2048, xh, xl, 2048);

        // a = exp(8*sigm(za)*logsig(lam)) -> slabB   (EPI=3, vvec=lam)
        gemm_sp<3, 0, 3, 0, 0, 0><<<dim3(16, 64), blk, 0, stream>>>(
            xh, xl, nullptr, nullptr, W_a, b_a, slabB, nullptr, nullptr, lam, nullptr,
            2048, 2048, 2048, 2048);
        // q = sqrt(1-a^2)*sigm(zg) -> dob            (EPI=4, Q=a)
        gemm_sp<3, 0, 4, 0, 0, 0><<<dim3(16, 64), blk, 0, stream>>>(
            xh, xl, nullptr, nullptr, W_g, b_g, dob, nullptr, slabB, nullptr, nullptr,
            2048, 2048, 2048, 2048);
        // b = q * (x@W_in^T + b_in) in place over dob (EPI=1, Q=C=dob)
        gemm_sp<3, 0, 1, 0, 0, 0><<<dim3(16, 64), blk, 0, stream>>>(
            xh, xl, nullptr, nullptr, W_in, b_in, dob, nullptr, dob, nullptr, nullptr,
            2048, 2048, 2048, 2048);

        // scan: a(slabB), b(dob) -> h fp32 over slabB
        scan_partial<<<dim3(8, SCAN_P), blk, 0, stream>>>(slabB, dob, Aagg, Bagg);
        scan_combine<<<8, blk, 0, stream>>>(Aagg, Bagg, Hini);
        scan_final<<<dim3(8, SCAN_P), blk, 0, stream>>>(slabB, dob, Hini);

        // ---- res1 = hHi @ W_outHi^T + b_out (NPROD=1, full DMA) ----
        u16* const hH  = (u16*)slabA;                  // [0:32MB)  (xh/xl dead)
        u16* const woH = hH + (1u << 24);              // [32:40MB)
        split_kernel<0><<<8192, blk, 0, stream>>>(slabB, 2048, hH, nullptr, 2048);
        split_kernel<0><<<2048, blk, 0, stream>>>(W_out, 2048, woH, nullptr, 2048);
        gemm_sp<1, 1, 0, 0, 0, 0><<<dim3(16, 64), blk, 0, stream>>>(
            hH, nullptr, woH, nullptr, nullptr, b_out, dob, nullptr, nullptr, nullptr, nullptr,
            2048, 2048, 2048, 2048);

        // gate1 + rmsnorm -> x1 split (hi/lo interleaved) in place over dob
        gate1s_kernel<<<8192, blk, 0, stream>>>(x, dob, slabB, v1, zc1, u1, n1w, n1b);

        // zb2 = zc2 (u-GEMM epilogues atomically accumulate the exact dot)
        zb2init_kernel<<<32, blk, 0, stream>>>(zb2, zc2);

        // ---- FFN over 4 F-chunks; u stored bf16-hi only; res2 -> slabB ----
        u16* const uH  = (u16*)slabA;                  // [0:32MB)  (hH dead)
        u16* const w1H = uH + (1u << 24);              // [32:40MB) (woH dead)
        u16* const w1L = w1H + (1u << 22);             // [40:48MB)
        u16* const w2H = w1H + (1u << 23);             // [48:56MB)
        u16* const x1h = (u16*)dob;                    // ldA=4096, lo at +2048
        for (int c = 0; c < 4; ++c) {
            const long f0 = (long)c << 11;
            split_kernel<1><<<2048, blk, 0, stream>>>(w1 + f0 * 2048, 2048, w1H, w1L, 2048);
            split_kernel<0><<<2048, blk, 0, stream>>>(w2 + f0, 8192, w2H, nullptr, 2048);
            // u = gelu(x1@w1c^T + b1c); store hi; fused zb2 += u . v2c
            gemm_sp<3, 1, 2, 0, 1, 1><<<dim3(16, 64), blk, 0, stream>>>(
                x1h, x1h + 2048, w1H, w1L, nullptr, fb1 + f0, nullptr, uH, nullptr,
                v2 + f0, zb2, 4096, 2048, 2048, 2048);
            if (c == 0)
                gemm_sp<1, 1, 0, 0, 0, 0><<<dim3(16, 64), blk, 0, stream>>>(
                    uH, nullptr, w2H, nullptr, nullptr, fb2, slabB, nullptr, nullptr,
                    nullptr, nullptr, 2048, 2048, 2048, 2048);
            else
                gemm_sp<1, 1, 0, 1, 0, 0><<<dim3(16, 64), blk, 0, stream>>>(
                    uH, nullptr, w2H, nullptr, nullptr, nullptr, slabB, nullptr, nullptr,
                    nullptr, nullptr, 2048, 2048, 2048, 2048);
        }
        gate2s_kernel<<<8192, blk, 0, stream>>>(dob, slabB, zb2, u2, n2w, n2b);
    } else {
        // ---------------- fallback: original path B, verbatim ----------------
        u16* uHi = (u16*)slabA;
        u16* uLo = uHi + (1u << 24);

        gemm_f32<0, 3, 0, 0, 0><<<dim3(16, 64), blk, 0, stream>>>(
            x, nullptr, W_a, b_a, slabA, nullptr, nullptr, nullptr, 2048, 2048, 2048, 2048);
        gemm_f32<0, 3, 0, 0, 0><<<dim3(16, 64), blk, 0, stream>>>(
            x, nullptr, W_g, b_g, dob, nullptr, nullptr, nullptr, 2048, 2048, 2048, 2048);
        aq_kernel<<<16384, blk, 0, stream>>>(slabA, dob, lam);
        gemm_f32<0, 3, 1, 0, 0><<<dim3(16, 64), blk, 0, stream>>>(
            x, nullptr, W_in, b_in, dob, nullptr, nullptr, dob, 2048, 2048, 2048, 2048);
        scan_partial<<<dim3(8, SCAN_P), blk, 0, stream>>>(slabA, dob, Aagg, Bagg);
        scan_combine<<<8, blk, 0, stream>>>(Aagg, Bagg, Hini);
        scan_final<<<dim3(8, SCAN_P), blk, 0, stream>>>(slabA, dob, Hini);
        gemm_f32<0, 1, 0, 0, 0><<<dim3(16, 64), blk, 0, stream>>>(
            slabA, nullptr, W_out, b_out, dob, nullptr, nullptr, nullptr, 2048, 2048, 2048, 2048);
        gate1_kernel<<<8192, blk, 0, stream>>>(x, dob, slabA, v1, zc1, u1, n1w, n1b);
        for (int rb = 0; rb < 4; ++rb) {
            const long roff = (long)rb * 2048;
            gemm_f32<0, 3, 2, 0, 1><<<dim3(64, 16), blk, 0, stream>>>(
                dob + roff * 2048, nullptr, w1, fb1,
                nullptr, uHi, uLo, nullptr, 2048, 2048, 8192, 2048);
            zacc_kernel<1><<<2048, blk, 0, stream>>>(uHi, uLo, v2, zc2, zb2 + roff, 8192);
            gemm_f32<1, 1, 0, 0, 0><<<dim3(16, 16), blk, 0, stream>>>(
                nullptr, uHi, w2, fb2, res2b, nullptr, nullptr, nullptr,
                8192, 8192, 2048, 8192);
            gate2_kernel<<<2048, blk, 0, stream>>>(
                dob + roff * 2048, res2b, zb2 + roff, u2 + roff, n2w, n2b);
        }
    }
}

// Round 2
// 2680.475 us; speedup vs baseline: 1.2535x; 1.0020x over previous
//
#include <hip/hip_runtime.h>

#define LDSW 40
#define SCAN_P 128
#define SCAN_L 64

typedef short short8 __attribute__((ext_vector_type(8)));
typedef float floatx4 __attribute__((ext_vector_type(4)));
typedef unsigned short u16;

__device__ __forceinline__ u16 bf16_rne(float v) {
    unsigned int u = __float_as_uint(v);
    u = u + 0x7fffu + ((u >> 16) & 1u);
    return (u16)(u >> 16);
}
__device__ __forceinline__ float bf16_to_f(u16 h) {
    return __uint_as_float(((unsigned int)h) << 16);
}
__device__ __forceinline__ float sigm(float x) { return 1.f / (1.f + expf(-x)); }
__device__ __forceinline__ float logsig(float x) {
    const float l = log1pf(expf(-fabsf(x)));
    return x >= 0.f ? -l : x - l;
}

// fp32 -> bf16 hi/lo split of 8 contiguous elements
__device__ __forceinline__ void cvt8(const float* p, short8& h8, short8& l8) {
    const float4 a = *(const float4*)p;
    const float4 b = *(const float4*)(p + 4);
    const float v[8] = {a.x, a.y, a.z, a.w, b.x, b.y, b.z, b.w};
#pragma unroll
    for (int j = 0; j < 8; ++j) {
        const u16 hh = bf16_rne(v[j]);
        h8[j] = (short)hh;
        l8[j] = (short)bf16_rne(v[j] - bf16_to_f(hh));
    }
}
__device__ __forceinline__ void cvt8h(const float* p, short8& h8) {
    const float4 a = *(const float4*)p;
    const float4 b = *(const float4*)(p + 4);
    const float v[8] = {a.x, a.y, a.z, a.w, b.x, b.y, b.z, b.w};
#pragma unroll
    for (int j = 0; j < 8; ++j) h8[j] = (short)bf16_rne(v[j]);
}

// async global -> LDS, 16B per lane, wave-uniform LDS base (HW adds lane*16)
__device__ __forceinline__ void gld16(const u16* g, u16* l) {
    __builtin_amdgcn_global_load_lds(
        (const __attribute__((address_space(1))) void*)g,
        (__attribute__((address_space(3))) void*)l, 16, 0, 0);
}

__device__ __forceinline__ void vmwait8() { asm volatile("s_waitcnt vmcnt(8)" ::: "memory"); }
__device__ __forceinline__ void vmwait4() { asm volatile("s_waitcnt vmcnt(4)" ::: "memory"); }
__device__ __forceinline__ void vmwait0() { asm volatile("s_waitcnt vmcnt(0)" ::: "memory"); }
__device__ __forceinline__ void lgwait0() { asm volatile("s_waitcnt lgkmcnt(0)" ::: "memory"); }
__device__ __forceinline__ void barr()    { asm volatile("s_barrier" ::: "memory"); }

// ---------------------------------------------------------------------------
// OLD kernel (kept verbatim for the small-workspace fallback path B).
// ---------------------------------------------------------------------------
template <int AFMT, int NPROD, int EPI, int ACC, int ST>
__global__ __launch_bounds__(256, 2) void gemm_f32(
    const float* __restrict__ Af, const u16* __restrict__ Au,
    const float* __restrict__ Bf, const float* __restrict__ bias,
    float* C, u16* Chi, u16* Clo, const float* Q,
    long ldA, long ldB, long ldC, int K)
{
    __shared__ __align__(16) u16 sAh[128 * LDSW];
    __shared__ __align__(16) u16 sBh[128 * LDSW];
    __shared__ __align__(16) u16 sAl[NPROD == 3 ? 128 * LDSW : 8];
    __shared__ __align__(16) u16 sBl[NPROD == 3 ? 128 * LDSW : 8];

    const int tid  = threadIdx.x;
    const int lane = tid & 63;
    const int wid  = tid >> 6;
    const int wm   = (wid >> 1) << 6;
    const int wn   = (wid & 1) << 6;
    const int m16  = lane & 15;
    const int kq   = lane >> 4;
    const int koff = kq << 3;
    const long bM  = (long)blockIdx.y << 7;
    const long bN  = (long)blockIdx.x << 7;
    const int sr   = tid >> 2;
    const int sc   = (tid & 3) << 3;

    floatx4 acc[4][4] = {};

#pragma unroll 1
    for (int k0 = 0; k0 < K; k0 += 32) {
        __syncthreads();
#pragma unroll
        for (int i = 0; i < 2; ++i) {
            const int r  = sr + (i << 6);
            const int ls = r * LDSW + sc;
            if constexpr (AFMT == 0) {
                if constexpr (NPROD == 3) {
                    short8 h8, l8;
                    cvt8(Af + (bM + r) * ldA + k0 + sc, h8, l8);
                    *(short8*)&sAh[ls] = h8;
                    *(short8*)&sAl[ls] = l8;
                } else {
                    short8 h8;
                    cvt8h(Af + (bM + r) * ldA + k0 + sc, h8);
                    *(short8*)&sAh[ls] = h8;
                }
            } else {
                *(short8*)&sAh[ls] = *(const short8*)(Au + (bM + r) * ldA + k0 + sc);
            }
            if constexpr (NPROD == 3) {
                short8 h8, l8;
                cvt8(Bf + (bN + r) * ldB + k0 + sc, h8, l8);
                *(short8*)&sBh[ls] = h8;
                *(short8*)&sBl[ls] = l8;
            } else {
                short8 h8;
                cvt8h(Bf + (bN + r) * ldB + k0 + sc, h8);
                *(short8*)&sBh[ls] = h8;
            }
        }
        __syncthreads();

        short8 ah[4], bh[4];
#pragma unroll
        for (int t = 0; t < 4; ++t) {
            ah[t] = *(const short8*)&sAh[(wm + t * 16 + m16) * LDSW + koff];
            bh[t] = *(const short8*)&sBh[(wn + t * 16 + m16) * LDSW + koff];
        }
#pragma unroll
        for (int mi = 0; mi < 4; ++mi)
#pragma unroll
            for (int ni = 0; ni < 4; ++ni)
                acc[mi][ni] = __builtin_amdgcn_mfma_f32_16x16x32_bf16(ah[mi], bh[ni], acc[mi][ni], 0, 0, 0);

        if constexpr (NPROD == 3) {
            short8 al[4], bl[4];
#pragma unroll
            for (int t = 0; t < 4; ++t) {
                al[t] = *(const short8*)&sAl[(wm + t * 16 + m16) * LDSW + koff];
                bl[t] = *(const short8*)&sBl[(wn + t * 16 + m16) * LDSW + koff];
            }
#pragma unroll
            for (int mi = 0; mi < 4; ++mi)
#pragma unroll
                for (int ni = 0; ni < 4; ++ni)
                    acc[mi][ni] = __builtin_amdgcn_mfma_f32_16x16x32_bf16(ah[mi], bl[ni], acc[mi][ni], 0, 0, 0);
#pragma unroll
            for (int mi = 0; mi < 4; ++mi)
#pragma unroll
                for (int ni = 0; ni < 4; ++ni)
                    acc[mi][ni] = __builtin_amdgcn_mfma_f32_16x16x32_bf16(al[mi], bh[ni], acc[mi][ni], 0, 0, 0);
        }
    }

    float bv[4];
#pragma unroll
    for (int ni = 0; ni < 4; ++ni) bv[ni] = bias ? bias[bN + wn + ni * 16 + m16] : 0.f;

#pragma unroll
    for (int mi = 0; mi < 4; ++mi) {
#pragma unroll
        for (int ni = 0; ni < 4; ++ni) {
#pragma unroll
            for (int r = 0; r < 4; ++r) {
                const long grow = bM + wm + mi * 16 + (kq << 2) + r;
                const long gcol = bN + wn + ni * 16 + m16;
                const long idx  = grow * ldC + gcol;
                float v = acc[mi][ni][r] + bv[ni];
                if constexpr (ACC) v += C[idx];
                if constexpr (EPI == 1) v *= Q[idx];
                if constexpr (EPI == 2)
                    v = 0.5f * v * (1.f + tanhf(0.7978845608028654f * (v + 0.044715f * v * v * v)));
                if constexpr (ST == 1) {
                    const u16 h = bf16_rne(v);
                    Chi[idx] = h;
                    Clo[idx] = bf16_rne(v - bf16_to_f(h));
                } else {
                    C[idx] = v;
                }
            }
        }
    }
}

// ---------------------------------------------------------------------------
// Phase-1 GEMM: A pre-split bf16 hi/lo via global_load_lds; B fp32 cvt
// in-kernel.  128x128 tile, 2-barrier loop (kept from round 1 - proven).
// EPI: 1 v*=Q, 3 a=exp(8*sigm(v)*logsig(vvec[col])), 4 v=sqrt(1-Q^2)*sigm(v).
// ---------------------------------------------------------------------------
template <int NPROD, int BFMT, int EPI, int ACC, int ST, int DOT>
__global__ __launch_bounds__(256, 2) void gemm_sp(
    const u16* __restrict__ Ah, const u16* __restrict__ Al,
    const u16* __restrict__ Bh, const u16* __restrict__ Bl,
    const float* __restrict__ Bf, const float* __restrict__ bias,
    float* C, u16* Chi, const float* Q,
    const float* __restrict__ vvec, float* dacc,
    long ldA, long ldB, long ldC, int K)
{
    __shared__ __align__(16) u16 sAh[128 * 32];
    __shared__ __align__(16) u16 sBh[128 * 32];
    __shared__ __align__(16) u16 sAl[NPROD == 3 ? 128 * 32 : 8];
    __shared__ __align__(16) u16 sBl[NPROD == 3 ? 128 * 32 : 8];

    const int tid  = threadIdx.x;
    const int lane = tid & 63;
    const int wid  = tid >> 6;
    const int wm   = (wid >> 1) << 6;
    const int wn   = (wid & 1) << 6;
    const int m16  = lane & 15;
    const int kq   = lane >> 4;
    const long bM  = (long)blockIdx.y << 7;
    const long bN  = (long)blockIdx.x << 7;

    const int  drow = (wid << 5) + (lane >> 2);
    const int  qsrc = (((lane & 3) ^ ((lane >> 3) & 3)) << 3);
    const long a0   = (bM + drow) * ldA + qsrc;
    const long a1   = a0 + 16 * ldA;
    const long b0   = (bN + drow) * ldB + qsrc;
    const long b1   = b0 + 16 * ldB;
    u16* const lA0  = &sAh[(wid << 5) << 5];
    u16* const lA1  = lA0 + 512;
    u16* const lB0  = &sBh[(wid << 5) << 5];
    u16* const lB1  = lB0 + 512;
    u16* const lAl0 = &sAl[NPROD == 3 ? ((wid << 5) << 5) : 0];
    u16* const lAl1 = lAl0 + (NPROD == 3 ? 512 : 0);
    u16* const lBl0 = &sBl[NPROD == 3 ? ((wid << 5) << 5) : 0];
    u16* const lBl1 = lBl0 + (NPROD == 3 ? 512 : 0);

    const int sr  = tid >> 2;
    const int sc  = (tid & 3) << 3;
    const int wch = (((tid & 3) ^ ((sr >> 1) & 3)) << 3);

    const int kr = ((kq ^ ((m16 >> 1) & 3)) << 3);

    floatx4 acc[4][4] = {};

#pragma unroll 1
    for (int k0 = 0; k0 < K; k0 += 32) {
        __syncthreads();
        gld16(Ah + a0 + k0, lA0);
        gld16(Ah + a1 + k0, lA1);
        if constexpr (NPROD == 3) {
            gld16(Al + a0 + k0, lAl0);
            gld16(Al + a1 + k0, lAl1);
        }
        if constexpr (BFMT == 1) {
            gld16(Bh + b0 + k0, lB0);
            gld16(Bh + b1 + k0, lB1);
            if constexpr (NPROD == 3) {
                gld16(Bl + b0 + k0, lBl0);
                gld16(Bl + b1 + k0, lBl1);
            }
        } else {
#pragma unroll
            for (int i = 0; i < 2; ++i) {
                const int r = sr + (i << 6);
                short8 h8, l8;
                cvt8(Bf + (bN + r) * ldB + k0 + sc, h8, l8);
                *(short8*)&sBh[(r << 5) + wch] = h8;
                *(short8*)&sBl[(r << 5) + wch] = l8;
            }
        }
        __syncthreads();

        short8 ah[4], bh[4];
#pragma unroll
        for (int t = 0; t < 4; ++t) {
            ah[t] = *(const short8*)&sAh[((wm + t * 16 + m16) << 5) + kr];
            bh[t] = *(const short8*)&sBh[((wn + t * 16 + m16) << 5) + kr];
        }
#pragma unroll
        for (int mi = 0; mi < 4; ++mi)
#pragma unroll
            for (int ni = 0; ni < 4; ++ni)
                acc[mi][ni] = __builtin_amdgcn_mfma_f32_16x16x32_bf16(ah[mi], bh[ni], acc[mi][ni], 0, 0, 0);

        if constexpr (NPROD == 3) {
            short8 al[4], bl[4];
#pragma unroll
            for (int t = 0; t < 4; ++t) {
                al[t] = *(const short8*)&sAl[((wm + t * 16 + m16) << 5) + kr];
                bl[t] = *(const short8*)&sBl[((wn + t * 16 + m16) << 5) + kr];
            }
#pragma unroll
            for (int mi = 0; mi < 4; ++mi)
#pragma unroll
                for (int ni = 0; ni < 4; ++ni)
                    acc[mi][ni] = __builtin_amdgcn_mfma_f32_16x16x32_bf16(ah[mi], bl[ni], acc[mi][ni], 0, 0, 0);
#pragma unroll
            for (int mi = 0; mi < 4; ++mi)
#pragma unroll
                for (int ni = 0; ni < 4; ++ni)
                    acc[mi][ni] = __builtin_amdgcn_mfma_f32_16x16x32_bf16(al[mi], bh[ni], acc[mi][ni], 0, 0, 0);
        }
    }

    float bv[4];
#pragma unroll
    for (int ni = 0; ni < 4; ++ni) bv[ni] = bias ? bias[bN + wn + ni * 16 + m16] : 0.f;
    float vv[4] = {}, ls[4] = {};
    if constexpr (EPI == 3 || DOT == 1) {
#pragma unroll
        for (int ni = 0; ni < 4; ++ni) {
            vv[ni] = vvec[bN + wn + ni * 16 + m16];
            if constexpr (EPI == 3) ls[ni] = logsig(vv[ni]);
        }
    }
    float ds[4][4] = {};

#pragma unroll
    for (int mi = 0; mi < 4; ++mi) {
#pragma unroll
        for (int ni = 0; ni < 4; ++ni) {
#pragma unroll
            for (int r = 0; r < 4; ++r) {
                // C/D: col = lane&15, row = (lane>>4)*4 + reg  [m89-verified]
                const long grow = bM + wm + mi * 16 + (kq << 2) + r;
                const long gcol = bN + wn + ni * 16 + m16;
                const long idx  = grow * ldC + gcol;
                float v = acc[mi][ni][r] + bv[ni];
                if constexpr (EPI == 1) v *= Q[idx];
                if constexpr (EPI == 2)
                    v = 0.5f * v * (1.f + tanhf(0.7978845608028654f * (v + 0.044715f * v * v * v)));
                if constexpr (EPI == 3) v = expf(8.f * sigm(v) * ls[ni]);
                if constexpr (EPI == 4) {
                    const float a = Q[idx];
                    v = sqrtf(fmaxf(1.f - a * a, 0.f)) * sigm(v);
                }
                if constexpr (ACC) v += C[idx];
                if constexpr (DOT) ds[mi][r] += v * vv[ni];
                if constexpr (ST == 1) Chi[idx] = bf16_rne(v);
                else C[idx] = v;
            }
        }
    }

    if constexpr (DOT) {
#pragma unroll
        for (int mi = 0; mi < 4; ++mi)
#pragma unroll
            for (int r = 0; r < 4; ++r) {
                float s = ds[mi][r];
                s += __shfl_xor(s, 1);
                s += __shfl_xor(s, 2);
                s += __shfl_xor(s, 4);
                s += __shfl_xor(s, 8);
                if (m16 == 0)
                    atomicAdd(&dacc[bM + wm + mi * 16 + (kq << 2) + r], s);
            }
    }
}

// ---------------------------------------------------------------------------
// 8-phase 256x256 GEMM (T3+T4+T5 per guide): operands pre-split bf16 planes
// in HBM.  512 thr = 8 waves (2M x 4N), 128x64 out/wave, BK=32, LDS
// double-buffer (NPROD=3: 2 x 4planes x 16KB = 128 KB).  Per K-tile: 4
// compute phases (one mi-pair quadrant each; B frags hoisted to regs in
// phase 0).  Prefetch t+2 issued in phase 3 after lgkmcnt(0)+barrier proves
// the buffer drained; counted vmcnt(L) (never 0 mid-loop) keeps next tile's
// loads in flight across barriers.  MFMA order per acc element (hh,hl,lh
// per K-tile) identical to gemm_sp -> bit-identical numerics.
// ---------------------------------------------------------------------------
template <int NPROD, int EPI, int ACC, int ST, int DOT>
__global__ __launch_bounds__(512, 2) void gemm8(
    const u16* __restrict__ Ah, const u16* __restrict__ Al,
    const u16* __restrict__ Bh, const u16* __restrict__ Bl,
    const float* __restrict__ bias,
    float* C, u16* Chi,
    const float* __restrict__ vvec, float* dacc,
    long ldA, long ldB, long ldC, int K)
{
    constexpr int NPL = (NPROD == 3) ? 4 : 2;   // [0]=Ah [1]=Bh [2]=Al [3]=Bl
    __shared__ __align__(16) u16 lds[2][NPL][8192];

    const int tid  = threadIdx.x;
    const int lane = tid & 63;
    const int wid  = tid >> 6;      // 0..7
    const int wr   = wid >> 2;      // 0..1 (M)
    const int wc   = wid & 3;       // 0..3 (N)
    const int m16  = lane & 15;
    const int kq   = lane >> 4;
    const long bM  = (long)blockIdx.y << 8;
    const long bN  = (long)blockIdx.x << 8;

    // staging: wave wid stages rows [wid*32, wid*32+32) of each plane,
    // 2 gld16 per plane (j = 0,16).  Linear LDS fill; source pre-swizzled.
    const int  drow = (wid << 5) + (lane >> 2);
    const int  qsrc = (((lane & 3) ^ ((lane >> 3) & 3)) << 3);
    const u16* gA0  = Ah + (bM + drow) * ldA + qsrc;
    const u16* gA1  = gA0 + (ldA << 4);
    const u16* gB0  = Bh + (bN + drow) * ldB + qsrc;
    const u16* gB1  = gB0 + (ldB << 4);
    const u16* gAl0 = (NPROD == 3 ? Al : Ah) + (bM + drow) * ldA + qsrc;
    const u16* gAl1 = gAl0 + (ldA << 4);
    const u16* gBl0 = (NPROD == 3 ? Bl : Bh) + (bN + drow) * ldB + qsrc;
    const u16* gBl1 = gBl0 + (ldB << 4);

    const int lwb = wid << 10;                        // wid*32 rows * 32 u16
    const int kr  = ((kq ^ ((m16 >> 1) & 3)) << 3);   // phys chunk on read

    const int NT = K >> 5;

    auto stage = [&](int buf, int t) {
        const long k0 = (long)t << 5;
        gld16(gA0 + k0, &lds[buf][0][lwb]);
        gld16(gA1 + k0, &lds[buf][0][lwb + 512]);
        gld16(gB0 + k0, &lds[buf][1][lwb]);
        gld16(gB1 + k0, &lds[buf][1][lwb + 512]);
        if constexpr (NPROD == 3) {
            gld16(gAl0 + k0, &lds[buf][2][lwb]);
            gld16(gAl1 + k0, &lds[buf][2][lwb + 512]);
            gld16(gBl0 + k0, &lds[buf][3][lwb]);
            gld16(gBl1 + k0, &lds[buf][3][lwb + 512]);
        }
    };

    floatx4 acc[8][4] = {};
    short8 bh[4], bl[4];

    stage(0, 0);
    stage(1, 1);
    if constexpr (NPROD == 3) vmwait8(); else vmwait4();
    barr();

    const int arow = (wr << 7) + m16;   // + mi*16
    const int brow = (wc << 6) + m16;   // + ni*16

#pragma unroll 1
    for (int t = 0; t < NT; ++t) {
        const int p = t & 1;
#pragma unroll
        for (int q = 0; q < 4; ++q) {
            const int r0 = arow + (q << 5);
            const int r1 = r0 + 16;
            short8 ah0 = *(const short8*)&lds[p][0][(r0 << 5) + kr];
            short8 ah1 = *(const short8*)&lds[p][0][(r1 << 5) + kr];
            short8 al0 = {}, al1 = {};
            if constexpr (NPROD == 3) {
                al0 = *(const short8*)&lds[p][2][(r0 << 5) + kr];
                al1 = *(const short8*)&lds[p][2][(r1 << 5) + kr];
            }
            if (q == 0) {
#pragma unroll
                for (int ni = 0; ni < 4; ++ni) {
                    const int rb = (brow + (ni << 4)) << 5;
                    bh[ni] = *(const short8*)&lds[p][1][rb + kr];
                    if constexpr (NPROD == 3)
                        bl[ni] = *(const short8*)&lds[p][3][rb + kr];
                }
            }
            if (q < 3) {
                lgwait0();
                __builtin_amdgcn_sched_barrier(0);
                __builtin_amdgcn_s_setprio(1);
#pragma unroll
                for (int ni = 0; ni < 4; ++ni) {
                    acc[2 * q][ni]     = __builtin_amdgcn_mfma_f32_16x16x32_bf16(ah0, bh[ni], acc[2 * q][ni], 0, 0, 0);
                    acc[2 * q + 1][ni] = __builtin_amdgcn_mfma_f32_16x16x32_bf16(ah1, bh[ni], acc[2 * q + 1][ni], 0, 0, 0);
                }
                if constexpr (NPROD == 3) {
#pragma unroll
                    for (int ni = 0; ni < 4; ++ni) {
                        acc[2 * q][ni]     = __builtin_amdgcn_mfma_f32_16x16x32_bf16(ah0, bl[ni], acc[2 * q][ni], 0, 0, 0);
                        acc[2 * q + 1][ni] = __builtin_amdgcn_mfma_f32_16x16x32_bf16(ah1, bl[ni], acc[2 * q + 1][ni], 0, 0, 0);
                    }
#pragma unroll
                    for (int ni = 0; ni < 4; ++ni) {
                        acc[2 * q][ni]     = __builtin_amdgcn_mfma_f32_16x16x32_bf16(al0, bh[ni], acc[2 * q][ni], 0, 0, 0);
                        acc[2 * q + 1][ni] = __builtin_amdgcn_mfma_f32_16x16x32_bf16(al1, bh[ni], acc[2 * q + 1][ni], 0, 0, 0);
                    }
                }
                __builtin_amdgcn_s_setprio(0);
                barr();
            } else {
                lgwait0();
                barr();   // all waves done reading buf p -> safe to restage
                const bool pf = (t + 2 < NT);
                if (pf) stage(p, t + 2);
                __builtin_amdgcn_s_setprio(1);
#pragma unroll
                for (int ni = 0; ni < 4; ++ni) {
                    acc[6][ni] = __builtin_amdgcn_mfma_f32_16x16x32_bf16(ah0, bh[ni], acc[6][ni], 0, 0, 0);
                    acc[7][ni] = __builtin_amdgcn_mfma_f32_16x16x32_bf16(ah1, bh[ni], acc[7][ni], 0, 0, 0);
                }
                if constexpr (NPROD == 3) {
#pragma unroll
                    for (int ni = 0; ni < 4; ++ni) {
                        acc[6][ni] = __builtin_amdgcn_mfma_f32_16x16x32_bf16(ah0, bl[ni], acc[6][ni], 0, 0, 0);
                        acc[7][ni] = __builtin_amdgcn_mfma_f32_16x16x32_bf16(ah1, bl[ni], acc[7][ni], 0, 0, 0);
                    }
#pragma unroll
                    for (int ni = 0; ni < 4; ++ni) {
                        acc[6][ni] = __builtin_amdgcn_mfma_f32_16x16x32_bf16(al0, bh[ni], acc[6][ni], 0, 0, 0);
                        acc[7][ni] = __builtin_amdgcn_mfma_f32_16x16x32_bf16(al1, bh[ni], acc[7][ni], 0, 0, 0);
                    }
                }
                __builtin_amdgcn_s_setprio(0);
                if (pf) {
                    if constexpr (NPROD == 3) vmwait8(); else vmwait4();
                } else {
                    vmwait0();
                }
                barr();
            }
        }
    }

    float bv[4];
#pragma unroll
    for (int ni = 0; ni < 4; ++ni) bv[ni] = bias ? bias[bN + (wc << 6) + (ni << 4) + m16] : 0.f;
    float vv[4] = {};
    if constexpr (DOT) {
#pragma unroll
        for (int ni = 0; ni < 4; ++ni) vv[ni] = vvec[bN + (wc << 6) + (ni << 4) + m16];
    }
    float ds[8][4] = {};

#pragma unroll
    for (int mi = 0; mi < 8; ++mi) {
#pragma unroll
        for (int ni = 0; ni < 4; ++ni) {
#pragma unroll
            for (int r = 0; r < 4; ++r) {
                const long grow = bM + (wr << 7) + (mi << 4) + (kq << 2) + r;
                const long gcol = bN + (wc << 6) + (ni << 4) + m16;
                const long idx  = grow * ldC + gcol;
                float v = acc[mi][ni][r] + bv[ni];
                if constexpr (EPI == 2)
                    v = 0.5f * v * (1.f + tanhf(0.7978845608028654f * (v + 0.044715f * v * v * v)));
                if constexpr (ACC) v += C[idx];
                if constexpr (DOT) ds[mi][r] += v * vv[ni];
                if constexpr (ST == 1) Chi[idx] = bf16_rne(v);
                else C[idx] = v;
            }
        }
    }

    if constexpr (DOT) {
#pragma unroll
        for (int mi = 0; mi < 8; ++mi)
#pragma unroll
            for (int r = 0; r < 4; ++r) {
                float s = ds[mi][r];
                s += __shfl_xor(s, 1);
                s += __shfl_xor(s, 2);
                s += __shfl_xor(s, 4);
                s += __shfl_xor(s, 8);
                if (m16 == 0)
                    atomicAdd(&dacc[bM + (wr << 7) + (mi << 4) + (kq << 2) + r], s);
            }
    }
}

// ---------------------------------------------------------------------------
// fp32 -> bf16 hi(/lo) planes.  One block per row, 2048 cols.
template <int HASLO>
__global__ __launch_bounds__(256) void split_kernel(
    const float* __restrict__ src, long lds,
    u16* __restrict__ hi, u16* __restrict__ lo, long ldd)
{
    const long r = blockIdx.x;
    const int  c = threadIdx.x << 3;
    const float* p = src + r * lds + c;
    const float4 a = *(const float4*)p;
    const float4 b = *(const float4*)(p + 4);
    const float v[8] = {a.x, a.y, a.z, a.w, b.x, b.y, b.z, b.w};
    short8 h8, l8;
#pragma unroll
    for (int j = 0; j < 8; ++j) {
        const u16 hh = bf16_rne(v[j]);
        h8[j] = (short)hh;
        if constexpr (HASLO) l8[j] = (short)bf16_rne(v[j] - bf16_to_f(hh));
    }
    *(short8*)&hi[r * ldd + c] = h8;
    if constexpr (HASLO) *(short8*)&lo[r * ldd + c] = l8;
}

__global__ __launch_bounds__(256) void zb2init_kernel(
    float* __restrict__ zb2, const float* __restrict__ zc2)
{
    zb2[blockIdx.x * 256 + threadIdx.x] = zc2[0];
}

// ---------------------------------------------------------------------------
// (fallback path B only)
__global__ __launch_bounds__(256) void aq_kernel(
    float* za, float* zg, const float* __restrict__ lam)
{
    const long i = ((long)blockIdx.x * 256 + threadIdx.x) * 4;
    const int  c = (int)(i & 2047);
    const float4 zav = *(const float4*)(za + i);
    const float4 zgv = *(const float4*)(zg + i);
    const float4 lmv = *(const float4*)(lam + c);
    float4 av, qv;
    const float zaa[4] = {zav.x, zav.y, zav.z, zav.w};
    const float zga[4] = {zgv.x, zgv.y, zgv.z, zgv.w};
    const float lma[4] = {lmv.x, lmv.y, lmv.z, lmv.w};
    float aa[4], qa[4];
#pragma unroll
    for (int j = 0; j < 4; ++j) {
        const float r  = sigm(zaa[j]);
        const float g  = sigm(zga[j]);
        const float la = 8.f * r * logsig(lma[j]);
        aa[j] = expf(la);
        qa[j] = sqrtf(fmaxf(1.f - expf(2.f * la), 0.f)) * g;
    }
    av.x = aa[0]; av.y = aa[1]; av.z = aa[2]; av.w = aa[3];
    qv.x = qa[0]; qv.y = qa[1]; qv.z = qa[2]; qv.w = qa[3];
    *(float4*)(za + i) = av;
    *(float4*)(zg + i) = qv;
}

// ---------------------------------------------------------------------------
// chunked scan over S (stride 2048): h_t = a_t h_{t-1} + b_t
__global__ __launch_bounds__(256) void scan_partial(
    const float* __restrict__ A, const float* __restrict__ B,
    float* __restrict__ Aagg, float* __restrict__ Bagg)
{
    const int c = blockIdx.x * 256 + threadIdx.x;
    const int p = blockIdx.y;
    const long base = (long)p * SCAN_L * 2048 + c;
    float Ar = 1.f, Br = 0.f;
    for (int t = 0; t < SCAN_L; ++t) {
        const float at = A[base + (long)t * 2048];
        const float bt = B[base + (long)t * 2048];
        Ar *= at;
        Br = Br * at + bt;
    }
    Aagg[p * 2048 + c] = Ar;
    Bagg[p * 2048 + c] = Br;
}

__global__ __launch_bounds__(256) void scan_combine(
    const float* __restrict__ Aagg, const float* __restrict__ Bagg,
    float* __restrict__ Hini)
{
    const int c = blockIdx.x * 256 + threadIdx.x;
    float h = 0.f;
    for (int p = 0; p < SCAN_P; ++p) {
        Hini[p * 2048 + c] = h;
        h = Aagg[p * 2048 + c] * h + Bagg[p * 2048 + c];
    }
}

// reads a (A) and b (B), writes h fp32 over A; optionally also bf16-hi plane
__global__ __launch_bounds__(256) void scan_final(
    float* A, const float* __restrict__ B, const float* __restrict__ Hini,
    u16* __restrict__ Hhi)
{
    const int c = blockIdx.x * 256 + threadIdx.x;
    const int p = blockIdx.y;
    const long base = (long)p * SCAN_L * 2048 + c;
    float h = Hini[p * 2048 + c];
    for (int t = 0; t < SCAN_L; ++t) {
        const long idx = base + (long)t * 2048;
        h = A[idx] * h + B[idx];
        A[idx] = h;
        if (Hhi) Hhi[idx] = bf16_rne(h);
    }
}

// ---------------------------------------------------------------------------
// v[j] = sum_d W[d,j] * w[d]   (chunked partials, then reduce)
__global__ __launch_bounds__(256) void vpart_kernel(
    const float* __restrict__ W, const float* __restrict__ w,
    float* __restrict__ part, long ldW, int dchunk)
{
    const int j  = blockIdx.x * 256 + threadIdx.x;
    const int d0 = blockIdx.y * dchunk;
    float s = 0.f;
    for (int d = 0; d < dchunk; ++d) s += W[(long)(d0 + d) * ldW + j] * w[d0 + d];
    part[(long)blockIdx.y * ldW + j] = s;
}

__global__ __launch_bounds__(256) void vreduce_kernel(
    const float* __restrict__ part, float* __restrict__ v, long ldW, int nch)
{
    const int j = blockIdx.x * 256 + threadIdx.x;
    float s = 0.f;
    for (int c = 0; c < nch; ++c) s += part[(long)c * ldW + j];
    v[j] = s;
}

__global__ __launch_bounds__(256) void dotc_kernel(
    const float* __restrict__ a, const float* __restrict__ b,
    const float* __restrict__ bias1, float* __restrict__ out)
{
    __shared__ float red[4];
    const int tid = threadIdx.x, lane = tid & 63, wid = tid >> 6;
    float s = 0.f;
    for (int d = tid; d < 2048; d += 256) s += a[d] * b[d];
#pragma unroll
    for (int off = 32; off > 0; off >>= 1) s += __shfl_down(s, off);
    if (lane == 0) red[wid] = s;
    __syncthreads();
    if (tid == 0) out[0] = red[0] + red[1] + red[2] + red[3] + bias1[0];
}

// ---------------------------------------------------------------------------
// (path B only)
template <int INIT>
__global__ __launch_bounds__(256) void zacc_kernel(
    const u16* __restrict__ uHi, const u16* __restrict__ uLo,
    const float* __restrict__ v2s, const float* __restrict__ zc,
    float* __restrict__ zb, int L)
{
    __shared__ float red[4];
    const int tid = threadIdx.x, lane = tid & 63, wid = tid >> 6;
    const long s = blockIdx.x;
    const long base = s * (long)L;
    float dot = 0.f;
    for (int f = tid; f < L; f += 256)
        dot += (bf16_to_f(uHi[base + f]) + bf16_to_f(uLo[base + f])) * v2s[f];
#pragma unroll
    for (int off = 32; off > 0; off >>= 1) dot += __shfl_down(dot, off);
    if (lane == 0) red[wid] = dot;
    __syncthreads();
    if (tid == 0) {
        const float t = red[0] + red[1] + red[2] + red[3];
        zb[s] = INIT ? (zc[0] + t) : (zb[s] + t);
    }
}

// ---------------------------------------------------------------------------
// gate1 (path B): fp32 x1 in place over res1
__global__ __launch_bounds__(256) void gate1_kernel(
    const float* __restrict__ x, float* res1x1,
    const float* __restrict__ h,
    const float* __restrict__ v1, const float* __restrict__ zc1,
    const float* __restrict__ u1,
    const float* __restrict__ nw, const float* __restrict__ nb)
{
    __shared__ float red[4];
    const int tid = threadIdx.x, lane = tid & 63, wid = tid >> 6;
    const long s = blockIdx.x;
    const long base = s * 2048;

    float dot = 0.f;
#pragma unroll
    for (int k = 0; k < 8; ++k) {
        const int d = tid + (k << 8);
        dot += h[base + d] * v1[d];
    }
#pragma unroll
    for (int off = 32; off > 0; off >>= 1) dot += __shfl_down(dot, off);
    if (lane == 0) red[wid] = dot;
    __syncthreads();
    const float z = red[0] + red[1] + red[2] + red[3] + zc1[0];
    __syncthreads();

    const float g = (u1[s] < sigm(z)) ? 1.f : 0.f;

    float yv[8];
    float ss = 0.f;
#pragma unroll
    for (int k = 0; k < 8; ++k) {
        const int d = tid + (k << 8);
        const float y = x[base + d] + g * res1x1[base + d];
        yv[k] = y;
        ss += y * y;
    }
#pragma unroll
    for (int off = 32; off > 0; off >>= 1) ss += __shfl_down(ss, off);
    if (lane == 0) red[wid] = ss;
    __syncthreads();
    const float inv = rsqrtf((red[0] + red[1] + red[2] + red[3]) * (1.f / 2048.f) + 1e-6f);

#pragma unroll
    for (int k = 0; k < 8; ++k) {
        const int d = tid + (k << 8);
        res1x1[base + d] = yv[k] * inv * nw[d] + nb[d];
    }
}

// gate1 (path A): writes x1 as row-interleaved bf16 hi/lo split, in place
__global__ __launch_bounds__(256) void gate1s_kernel(
    const float* __restrict__ x, float* res1x1,
    const float* __restrict__ h,
    const float* __restrict__ v1, const float* __restrict__ zc1,
    const float* __restrict__ u1,
    const float* __restrict__ nw, const float* __restrict__ nb)
{
    __shared__ float red[4];
    const int tid = threadIdx.x, lane = tid & 63, wid = tid >> 6;
    const long s = blockIdx.x;
    const long base = s * 2048;

    float dot = 0.f;
#pragma unroll
    for (int k = 0; k < 8; ++k) {
        const int d = tid + (k << 8);
        dot += h[base + d] * v1[d];
    }
#pragma unroll
    for (int off = 32; off > 0; off >>= 1) dot += __shfl_down(dot, off);
    if (lane == 0) red[wid] = dot;
    __syncthreads();
    const float z = red[0] + red[1] + red[2] + red[3] + zc1[0];
    __syncthreads();

    const float g = (u1[s] < sigm(z)) ? 1.f : 0.f;

    float yv[8];
    float ss = 0.f;
#pragma unroll
    for (int k = 0; k < 8; ++k) {
        const int d = tid + (k << 8);
        const float y = x[base + d] + g * res1x1[base + d];
        yv[k] = y;
        ss += y * y;
    }
#pragma unroll
    for (int off = 32; off > 0; off >>= 1) ss += __shfl_down(ss, off);
    if (lane == 0) red[wid] = ss;
    __syncthreads();
    const float inv = rsqrtf((red[0] + red[1] + red[2] + red[3]) * (1.f / 2048.f) + 1e-6f);

    u16* xs = (u16*)res1x1;
    const long sb = s * 4096;
#pragma unroll
    for (int k = 0; k < 8; ++k) {
        const int d = tid + (k << 8);
        const float o = yv[k] * inv * nw[d] + nb[d];
        const u16 hh = bf16_rne(o);
        xs[sb + d] = hh;
        xs[sb + 2048 + d] = bf16_rne(o - bf16_to_f(hh));
    }
}

// gate2 (path B)
__global__ __launch_bounds__(256) void gate2_kernel(
    float* x1out, const float* __restrict__ res2,
    const float* __restrict__ zb2, const float* __restrict__ u2,
    const float* __restrict__ nw, const float* __restrict__ nb)
{
    __shared__ float red[4];
    const int tid = threadIdx.x, lane = tid & 63, wid = tid >> 6;
    const long s = blockIdx.x;
    const long base = s * 2048;

    const float g = (u2[s] < sigm(zb2[s])) ? 1.f : 0.f;

    float yv[8];
    float ss = 0.f;
#pragma unroll
    for (int k = 0; k < 8; ++k) {
        const int d = tid + (k << 8);
        const float y = x1out[base + d] + g * res2[base + d];
        yv[k] = y;
        ss += y * y;
    }
#pragma unroll
    for (int off = 32; off > 0; off >>= 1) ss += __shfl_down(ss, off);
    if (lane == 0) red[wid] = ss;
    __syncthreads();
    const float inv = rsqrtf((red[0] + red[1] + red[2] + red[3]) * (1.f / 2048.f) + 1e-6f);

#pragma unroll
    for (int k = 0; k < 8; ++k) {
        const int d = tid + (k << 8);
        x1out[base + d] = yv[k] * inv * nw[d] + nb[d];
    }
}

// gate2 (path A): x1 reconstructed from hi+lo split; fp32 out in place.
__global__ __launch_bounds__(256) void gate2s_kernel(
    float* x1out, const float* __restrict__ res2,
    const float* __restrict__ zb2, const float* __restrict__ u2,
    const float* __restrict__ nw, const float* __restrict__ nb)
{
    __shared__ float red[4];
    const int tid = threadIdx.x, lane = tid & 63, wid = tid >> 6;
    const long s = blockIdx.x;
    const long base = s * 2048;
    const u16* xs = (const u16*)x1out;
    const long sb = s * 4096;

    const float g = (u2[s] < sigm(zb2[s])) ? 1.f : 0.f;

    float yv[8];
    float ss = 0.f;
#pragma unroll
    for (int k = 0; k < 8; ++k) {
        const int d = tid + (k << 8);
        const float x1 = bf16_to_f(xs[sb + d]) + bf16_to_f(xs[sb + 2048 + d]);
        const float y = x1 + g * res2[base + d];
        yv[k] = y;
        ss += y * y;
    }
#pragma unroll
    for (int off = 32; off > 0; off >>= 1) ss += __shfl_down(ss, off);
    if (lane == 0) red[wid] = ss;
    __syncthreads();
    const float inv = rsqrtf((red[0] + red[1] + red[2] + red[3]) * (1.f / 2048.f) + 1e-6f);

#pragma unroll
    for (int k = 0; k < 8; ++k) {
        const int d = tid + (k << 8);
        x1out[base + d] = yv[k] * inv * nw[d] + nb[d];
    }
}

// ---------------------------------------------------------------------------
extern "C" void kernel_launch(void* const* d_in, const int* in_sizes, int n_in,
                              void* d_out, int out_size, void* d_ws, size_t ws_size,
                              hipStream_t stream)
{
    const float* x     = (const float*)d_in[0];
    const float* W_in  = (const float*)d_in[1];
    const float* b_in  = (const float*)d_in[2];
    const float* W_a   = (const float*)d_in[3];
    const float* b_a   = (const float*)d_in[4];
    const float* W_g   = (const float*)d_in[5];
    const float* b_g   = (const float*)d_in[6];
    const float* lam   = (const float*)d_in[7];
    const float* W_out = (const float*)d_in[8];
    const float* b_out = (const float*)d_in[9];
    const float* w1    = (const float*)d_in[10];
    const float* fb1   = (const float*)d_in[11];
    const float* w2    = (const float*)d_in[12];
    const float* fb2   = (const float*)d_in[13];
    const float* a1w   = (const float*)d_in[14];
    const float* a1b   = (const float*)d_in[15];
    const float* a2w   = (const float*)d_in[16];
    const float* a2b   = (const float*)d_in[17];
    const float* n1w   = (const float*)d_in[18];
    const float* n1b   = (const float*)d_in[19];
    const float* n2w   = (const float*)d_in[20];
    const float* n2b   = (const float*)d_in[21];
    const float* u1    = (const float*)d_in[22];
    const float* u2    = (const float*)d_in[23];
    (void)in_sizes; (void)n_in; (void)out_size;

    float* dob = (float*)d_out;          // 64 MiB fp32 scratch until final write

    char* ws = (char*)d_ws;
    size_t o = 0;
    auto take = [&](size_t bytes) -> char* {
        char* p = ws + o;
        o += (bytes + 255) & ~(size_t)255;
        return p;
    };

    float* Aagg = (float*)take((size_t)SCAN_P * 2048 * 4);
    float* Bagg = (float*)take((size_t)SCAN_P * 2048 * 4);
    float* Hini = (float*)take((size_t)SCAN_P * 2048 * 4);
    float* v1   = (float*)take(2048 * 4);
    float* v2   = (float*)take(8192 * 4);
    float* vp   = (float*)take(16 * 8192 * 4);
    float* zc1  = (float*)take(256);
    float* zc2  = (float*)take(256);
    float* zb2  = (float*)take(8192 * 4);

    float* slabA = (float*)take(64ull << 20);
    const bool pathA = ws_size >= o + (64ull << 20);
    float* slabB = nullptr;
    float* res2b = nullptr;
    if (pathA) slabB = (float*)take(64ull << 20);
    else       res2b = (float*)take(16ull << 20);
    if (o > ws_size) return;  // diagnostic: absmax == max|ref| signature

    const dim3 blk(256);

    // gate-logit vectors (exact fp32 path; gates never see GEMM error)
    vpart_kernel<<<dim3(8, 16), blk, 0, stream>>>(W_out, a1w, vp, 2048, 128);
    vreduce_kernel<<<8, blk, 0, stream>>>(vp, v1, 2048, 16);
    vpart_kernel<<<dim3(32, 16), blk, 0, stream>>>(w2, a2w, vp, 8192, 128);
    vreduce_kernel<<<32, blk, 0, stream>>>(vp, v2, 8192, 16);
    dotc_kernel<<<1, blk, 0, stream>>>(b_out, a1w, a1b, zc1);
    dotc_kernel<<<1, blk, 0, stream>>>(fb2, a2w, a2b, zc2);

    if (pathA) {
        // ---- phase 1: pre-split A(x); B weights cvt in-kernel (ws-bound) ----
        u16* const xh = (u16*)slabA;
        u16* const xl = xh + (1u << 24);
        split_kernel<1><<<8192, blk, 0, stream>>>(x, 2048, xh, xl, 2048);

        // a = exp(8*sigm(za)*logsig(lam)) -> slabB   (EPI=3, vvec=lam)
        gemm_sp<3, 0, 3, 0, 0, 0><<<dim3(16, 64), blk, 0, stream>>>(
            xh, xl, nullptr, nullptr, W_a, b_a, slabB, nullptr, nullptr, lam, nullptr,
            2048, 2048, 2048, 2048);
        // q = sqrt(1-a^2)*sigm(zg) -> dob            (EPI=4, Q=a)
        gemm_sp<3, 0, 4, 0, 0, 0><<<dim3(16, 64), blk, 0, stream>>>(
            xh, xl, nullptr, nullptr, W_g, b_g, dob, nullptr, slabB, nullptr, nullptr,
            2048, 2048, 2048, 2048);
        // b = q * (x@W_in^T + b_in) in place over dob (EPI=1, Q=C=dob)
        gemm_sp<3, 0, 1, 0, 0, 0><<<dim3(16, 64), blk, 0, stream>>>(
            xh, xl, nullptr, nullptr, W_in, b_in, dob, nullptr, dob, nullptr, nullptr,
            2048, 2048, 2048, 2048);

        // scan: a(slabB), b(dob) -> h fp32 over slabB, bf16-hi plane -> slabA
        u16* const hH = (u16*)slabA;                   // xh/xl dead after b-GEMM
        scan_partial<<<dim3(8, SCAN_P), blk, 0, stream>>>(slabB, dob, Aagg, Bagg);
        scan_combine<<<8, blk, 0, stream>>>(Aagg, Bagg, Hini);
        scan_final<<<dim3(8, SCAN_P), blk, 0, stream>>>(slabB, dob, Hini, hH);

        // ---- res1 = hHi @ W_outHi^T + b_out (NPROD=1, 8-phase) ----
        u16* const woH = hH + (1u << 24);              // [32:40MB)
        split_kernel<0><<<2048, blk, 0, stream>>>(W_out, 2048, woH, nullptr, 2048);
        gemm8<1, 0, 0, 0, 0><<<dim3(8, 32), dim3(512), 0, stream>>>(
            hH, nullptr, woH, nullptr, b_out, dob, nullptr, nullptr, nullptr,
            2048, 2048, 2048, 2048);

        // gate1 + rmsnorm -> x1 split (hi/lo interleaved) in place over dob
        gate1s_kernel<<<8192, blk, 0, stream>>>(x, dob, slabB, v1, zc1, u1, n1w, n1b);

        // zb2 = zc2 (u-GEMM epilogues atomically accumulate the exact dot)
        zb2init_kernel<<<32, blk, 0, stream>>>(zb2, zc2);

        // ---- FFN over 4 F-chunks; u stored bf16-hi only; res2 -> slabB ----
        u16* const uH  = (u16*)slabA;                  // [0:32MB)  (hH dead)
        u16* const w1H = uH + (1u << 24);              // [32:40MB) (woH dead)
        u16* const w1L = w1H + (1u << 22);             // [40:48MB)
        u16* const w2H = w1H + (1u << 23);             // [48:56MB)
        u16* const x1h = (u16*)dob;                    // ldA=4096, lo at +2048
        for (int c = 0; c < 4; ++c) {
            const long f0 = (long)c << 11;
            split_kernel<1><<<2048, blk, 0, stream>>>(w1 + f0 * 2048, 2048, w1H, w1L, 2048);
            split_kernel<0><<<2048, blk, 0, stream>>>(w2 + f0, 8192, w2H, nullptr, 2048);
            // u = gelu(x1@w1c^T + b1c); store hi; fused zb2 += u . v2c
            gemm8<3, 2, 0, 1, 1><<<dim3(8, 32), dim3(512), 0, stream>>>(
                x1h, x1h + 2048, w1H, w1L, fb1 + f0, nullptr, uH,
                v2 + f0, zb2, 4096, 2048, 2048, 2048);
            if (c == 0)
                gemm8<1, 0, 0, 0, 0><<<dim3(8, 32), dim3(512), 0, stream>>>(
                    uH, nullptr, w2H, nullptr, fb2, slabB, nullptr, nullptr, nullptr,
                    2048, 2048, 2048, 2048);
            else
                gemm8<1, 0, 1, 0, 0><<<dim3(8, 32), dim3(512), 0, stream>>>(
                    uH, nullptr, w2H, nullptr, nullptr, slabB, nullptr, nullptr, nullptr,
                    2048, 2048, 2048, 2048);
        }
        gate2s_kernel<<<8192, blk, 0, stream>>>(dob, slabB, zb2, u2, n2w, n2b);
    } else {
        // ---------------- fallback: original path B, verbatim ----------------
        u16* uHi = (u16*)slabA;
        u16* uLo = uHi + (1u << 24);

        gemm_f32<0, 3, 0, 0, 0><<<dim3(16, 64), blk, 0, stream>>>(
            x, nullptr, W_a, b_a, slabA, nullptr, nullptr, nullptr, 2048, 2048, 2048, 2048);
        gemm_f32<0, 3, 0, 0, 0><<<dim3(16, 64), blk, 0, stream>>>(
            x, nullptr, W_g, b_g, dob, nullptr, nullptr, nullptr, 2048, 2048, 2048, 2048);
        aq_kernel<<<16384, blk, 0, stream>>>(slabA, dob, lam);
        gemm_f32<0, 3, 1, 0, 0><<<dim3(16, 64), blk, 0, stream>>>(
            x, nullptr, W_in, b_in, dob, nullptr, nullptr, dob, 2048, 2048, 2048, 2048);
        scan_partial<<<dim3(8, SCAN_P), blk, 0, stream>>>(slabA, dob, Aagg, Bagg);
        scan_combine<<<8, blk, 0, stream>>>(Aagg, Bagg, Hini);
        scan_final<<<dim3(8, SCAN_P), blk, 0, stream>>>(slabA, dob, Hini, nullptr);
        gemm_f32<0, 1, 0, 0, 0><<<dim3(16, 64), blk, 0, stream>>>(
            slabA, nullptr, W_out, b_out, dob, nullptr, nullptr, nullptr, 2048, 2048, 2048, 2048);
        gate1_kernel<<<8192, blk, 0, stream>>>(x, dob, slabA, v1, zc1, u1, n1w, n1b);
        for (int rb = 0; rb < 4; ++rb) {
            const long roff = (long)rb * 2048;
            gemm_f32<0, 3, 2, 0, 1><<<dim3(64, 16), blk, 0, stream>>>(
                dob + roff * 2048, nullptr, w1, fb1,
                nullptr, uHi, uLo, nullptr, 2048, 2048, 8192, 2048);
            zacc_kernel<1><<<2048, blk, 0, stream>>>(uHi, uLo, v2, zc2, zb2 + roff, 8192);
            gemm_f32<1, 1, 0, 0, 0><<<dim3(16, 16), blk, 0, stream>>>(
                nullptr, uHi, w2, fb2, res2b, nullptr, nullptr, nullptr,
                8192, 8192, 2048, 8192);
            gate2_kernel<<<2048, blk, 0, stream>>>(
                dob + roff * 2048, res2b, zb2 + roff, u2 + roff, n2w, n2b);
        }
    }
}

// Round 3
// 2216.397 us; speedup vs baseline: 1.5160x; 1.2094x over previous
//
#include <hip/hip_runtime.h>

#define LDSW 40
#define SCAN_P 128
#define SCAN_L 64

typedef short short8 __attribute__((ext_vector_type(8)));
typedef float floatx4 __attribute__((ext_vector_type(4)));
typedef unsigned short u16;

__device__ __forceinline__ u16 bf16_rne(float v) {
    unsigned int u = __float_as_uint(v);
    u = u + 0x7fffu + ((u >> 16) & 1u);
    return (u16)(u >> 16);
}
__device__ __forceinline__ float bf16_to_f(u16 h) {
    return __uint_as_float(((unsigned int)h) << 16);
}
__device__ __forceinline__ float sigm(float x) { return 1.f / (1.f + expf(-x)); }
__device__ __forceinline__ float logsig(float x) {
    const float l = log1pf(expf(-fabsf(x)));
    return x >= 0.f ? -l : x - l;
}

// fp32 -> bf16 hi/lo split of 8 contiguous elements
__device__ __forceinline__ void cvt8(const float* p, short8& h8, short8& l8) {
    const float4 a = *(const float4*)p;
    const float4 b = *(const float4*)(p + 4);
    const float v[8] = {a.x, a.y, a.z, a.w, b.x, b.y, b.z, b.w};
#pragma unroll
    for (int j = 0; j < 8; ++j) {
        const u16 hh = bf16_rne(v[j]);
        h8[j] = (short)hh;
        l8[j] = (short)bf16_rne(v[j] - bf16_to_f(hh));
    }
}
__device__ __forceinline__ void cvt8h(const float* p, short8& h8) {
    const float4 a = *(const float4*)p;
    const float4 b = *(const float4*)(p + 4);
    const float v[8] = {a.x, a.y, a.z, a.w, b.x, b.y, b.z, b.w};
#pragma unroll
    for (int j = 0; j < 8; ++j) h8[j] = (short)bf16_rne(v[j]);
}

// async global -> LDS, 16B per lane, wave-uniform LDS base (HW adds lane*16)
__device__ __forceinline__ void gld16(const u16* g, u16* l) {
    __builtin_amdgcn_global_load_lds(
        (const __attribute__((address_space(1))) void*)g,
        (__attribute__((address_space(3))) void*)l, 16, 0, 0);
}

__device__ __forceinline__ void vmwait8() { asm volatile("s_waitcnt vmcnt(8)" ::: "memory"); }
__device__ __forceinline__ void vmwait4() { asm volatile("s_waitcnt vmcnt(4)" ::: "memory"); }
__device__ __forceinline__ void vmwait0() { asm volatile("s_waitcnt vmcnt(0)" ::: "memory"); }
__device__ __forceinline__ void lgwait0() { asm volatile("s_waitcnt lgkmcnt(0)" ::: "memory"); }
__device__ __forceinline__ void barr()    { asm volatile("s_barrier" ::: "memory"); }

// ---------------------------------------------------------------------------
// OLD kernel (kept verbatim for the small-workspace fallback path B).
// ---------------------------------------------------------------------------
template <int AFMT, int NPROD, int EPI, int ACC, int ST>
__global__ __launch_bounds__(256, 2) void gemm_f32(
    const float* __restrict__ Af, const u16* __restrict__ Au,
    const float* __restrict__ Bf, const float* __restrict__ bias,
    float* C, u16* Chi, u16* Clo, const float* Q,
    long ldA, long ldB, long ldC, int K)
{
    __shared__ __align__(16) u16 sAh[128 * LDSW];
    __shared__ __align__(16) u16 sBh[128 * LDSW];
    __shared__ __align__(16) u16 sAl[NPROD == 3 ? 128 * LDSW : 8];
    __shared__ __align__(16) u16 sBl[NPROD == 3 ? 128 * LDSW : 8];

    const int tid  = threadIdx.x;
    const int lane = tid & 63;
    const int wid  = tid >> 6;
    const int wm   = (wid >> 1) << 6;
    const int wn   = (wid & 1) << 6;
    const int m16  = lane & 15;
    const int kq   = lane >> 4;
    const int koff = kq << 3;
    const long bM  = (long)blockIdx.y << 7;
    const long bN  = (long)blockIdx.x << 7;
    const int sr   = tid >> 2;
    const int sc   = (tid & 3) << 3;

    floatx4 acc[4][4] = {};

#pragma unroll 1
    for (int k0 = 0; k0 < K; k0 += 32) {
        __syncthreads();
#pragma unroll
        for (int i = 0; i < 2; ++i) {
            const int r  = sr + (i << 6);
            const int ls = r * LDSW + sc;
            if constexpr (AFMT == 0) {
                if constexpr (NPROD == 3) {
                    short8 h8, l8;
                    cvt8(Af + (bM + r) * ldA + k0 + sc, h8, l8);
                    *(short8*)&sAh[ls] = h8;
                    *(short8*)&sAl[ls] = l8;
                } else {
                    short8 h8;
                    cvt8h(Af + (bM + r) * ldA + k0 + sc, h8);
                    *(short8*)&sAh[ls] = h8;
                }
            } else {
                *(short8*)&sAh[ls] = *(const short8*)(Au + (bM + r) * ldA + k0 + sc);
            }
            if constexpr (NPROD == 3) {
                short8 h8, l8;
                cvt8(Bf + (bN + r) * ldB + k0 + sc, h8, l8);
                *(short8*)&sBh[ls] = h8;
                *(short8*)&sBl[ls] = l8;
            } else {
                short8 h8;
                cvt8h(Bf + (bN + r) * ldB + k0 + sc, h8);
                *(short8*)&sBh[ls] = h8;
            }
        }
        __syncthreads();

        short8 ah[4], bh[4];
#pragma unroll
        for (int t = 0; t < 4; ++t) {
            ah[t] = *(const short8*)&sAh[(wm + t * 16 + m16) * LDSW + koff];
            bh[t] = *(const short8*)&sBh[(wn + t * 16 + m16) * LDSW + koff];
        }
#pragma unroll
        for (int mi = 0; mi < 4; ++mi)
#pragma unroll
            for (int ni = 0; ni < 4; ++ni)
                acc[mi][ni] = __builtin_amdgcn_mfma_f32_16x16x32_bf16(ah[mi], bh[ni], acc[mi][ni], 0, 0, 0);

        if constexpr (NPROD == 3) {
            short8 al[4], bl[4];
#pragma unroll
            for (int t = 0; t < 4; ++t) {
                al[t] = *(const short8*)&sAl[(wm + t * 16 + m16) * LDSW + koff];
                bl[t] = *(const short8*)&sBl[(wn + t * 16 + m16) * LDSW + koff];
            }
#pragma unroll
            for (int mi = 0; mi < 4; ++mi)
#pragma unroll
                for (int ni = 0; ni < 4; ++ni)
                    acc[mi][ni] = __builtin_amdgcn_mfma_f32_16x16x32_bf16(ah[mi], bl[ni], acc[mi][ni], 0, 0, 0);
#pragma unroll
            for (int mi = 0; mi < 4; ++mi)
#pragma unroll
                for (int ni = 0; ni < 4; ++ni)
                    acc[mi][ni] = __builtin_amdgcn_mfma_f32_16x16x32_bf16(al[mi], bh[ni], acc[mi][ni], 0, 0, 0);
        }
    }

    float bv[4];
#pragma unroll
    for (int ni = 0; ni < 4; ++ni) bv[ni] = bias ? bias[bN + wn + ni * 16 + m16] : 0.f;

#pragma unroll
    for (int mi = 0; mi < 4; ++mi) {
#pragma unroll
        for (int ni = 0; ni < 4; ++ni) {
#pragma unroll
            for (int r = 0; r < 4; ++r) {
                const long grow = bM + wm + mi * 16 + (kq << 2) + r;
                const long gcol = bN + wn + ni * 16 + m16;
                const long idx  = grow * ldC + gcol;
                float v = acc[mi][ni][r] + bv[ni];
                if constexpr (ACC) v += C[idx];
                if constexpr (EPI == 1) v *= Q[idx];
                if constexpr (EPI == 2)
                    v = 0.5f * v * (1.f + tanhf(0.7978845608028654f * (v + 0.044715f * v * v * v)));
                if constexpr (ST == 1) {
                    const u16 h = bf16_rne(v);
                    Chi[idx] = h;
                    Clo[idx] = bf16_rne(v - bf16_to_f(h));
                } else {
                    C[idx] = v;
                }
            }
        }
    }
}

// ---------------------------------------------------------------------------
// Fallback phase-1 GEMM (no slabW): A pre-split via global_load_lds; B fp32
// cvt in-kernel.  128x128 tile, 2-barrier loop (round-1 proven).
// ---------------------------------------------------------------------------
template <int NPROD, int BFMT, int EPI, int ACC, int ST, int DOT>
__global__ __launch_bounds__(256, 2) void gemm_sp(
    const u16* __restrict__ Ah, const u16* __restrict__ Al,
    const u16* __restrict__ Bh, const u16* __restrict__ Bl,
    const float* __restrict__ Bf, const float* __restrict__ bias,
    float* C, u16* Chi, const float* Q,
    const float* __restrict__ vvec, float* dacc,
    long ldA, long ldB, long ldC, int K)
{
    __shared__ __align__(16) u16 sAh[128 * 32];
    __shared__ __align__(16) u16 sBh[128 * 32];
    __shared__ __align__(16) u16 sAl[NPROD == 3 ? 128 * 32 : 8];
    __shared__ __align__(16) u16 sBl[NPROD == 3 ? 128 * 32 : 8];

    const int tid  = threadIdx.x;
    const int lane = tid & 63;
    const int wid  = tid >> 6;
    const int wm   = (wid >> 1) << 6;
    const int wn   = (wid & 1) << 6;
    const int m16  = lane & 15;
    const int kq   = lane >> 4;
    const long bM  = (long)blockIdx.y << 7;
    const long bN  = (long)blockIdx.x << 7;

    const int  drow = (wid << 5) + (lane >> 2);
    const int  qsrc = (((lane & 3) ^ ((lane >> 3) & 3)) << 3);
    const long a0   = (bM + drow) * ldA + qsrc;
    const long a1   = a0 + 16 * ldA;
    const long b0   = (bN + drow) * ldB + qsrc;
    const long b1   = b0 + 16 * ldB;
    u16* const lA0  = &sAh[(wid << 5) << 5];
    u16* const lA1  = lA0 + 512;
    u16* const lB0  = &sBh[(wid << 5) << 5];
    u16* const lB1  = lB0 + 512;
    u16* const lAl0 = &sAl[NPROD == 3 ? ((wid << 5) << 5) : 0];
    u16* const lAl1 = lAl0 + (NPROD == 3 ? 512 : 0);
    u16* const lBl0 = &sBl[NPROD == 3 ? ((wid << 5) << 5) : 0];
    u16* const lBl1 = lBl0 + (NPROD == 3 ? 512 : 0);

    const int sr  = tid >> 2;
    const int sc  = (tid & 3) << 3;
    const int wch = (((tid & 3) ^ ((sr >> 1) & 3)) << 3);

    const int kr = ((kq ^ ((m16 >> 1) & 3)) << 3);

    floatx4 acc[4][4] = {};

#pragma unroll 1
    for (int k0 = 0; k0 < K; k0 += 32) {
        __syncthreads();
        gld16(Ah + a0 + k0, lA0);
        gld16(Ah + a1 + k0, lA1);
        if constexpr (NPROD == 3) {
            gld16(Al + a0 + k0, lAl0);
            gld16(Al + a1 + k0, lAl1);
        }
        if constexpr (BFMT == 1) {
            gld16(Bh + b0 + k0, lB0);
            gld16(Bh + b1 + k0, lB1);
            if constexpr (NPROD == 3) {
                gld16(Bl + b0 + k0, lBl0);
                gld16(Bl + b1 + k0, lBl1);
            }
        } else {
#pragma unroll
            for (int i = 0; i < 2; ++i) {
                const int r = sr + (i << 6);
                short8 h8, l8;
                cvt8(Bf + (bN + r) * ldB + k0 + sc, h8, l8);
                *(short8*)&sBh[(r << 5) + wch] = h8;
                *(short8*)&sBl[(r << 5) + wch] = l8;
            }
        }
        __syncthreads();

        short8 ah[4], bh[4];
#pragma unroll
        for (int t = 0; t < 4; ++t) {
            ah[t] = *(const short8*)&sAh[((wm + t * 16 + m16) << 5) + kr];
            bh[t] = *(const short8*)&sBh[((wn + t * 16 + m16) << 5) + kr];
        }
#pragma unroll
        for (int mi = 0; mi < 4; ++mi)
#pragma unroll
            for (int ni = 0; ni < 4; ++ni)
                acc[mi][ni] = __builtin_amdgcn_mfma_f32_16x16x32_bf16(ah[mi], bh[ni], acc[mi][ni], 0, 0, 0);

        if constexpr (NPROD == 3) {
            short8 al[4], bl[4];
#pragma unroll
            for (int t = 0; t < 4; ++t) {
                al[t] = *(const short8*)&sAl[((wm + t * 16 + m16) << 5) + kr];
                bl[t] = *(const short8*)&sBl[((wn + t * 16 + m16) << 5) + kr];
            }
#pragma unroll
            for (int mi = 0; mi < 4; ++mi)
#pragma unroll
                for (int ni = 0; ni < 4; ++ni)
                    acc[mi][ni] = __builtin_amdgcn_mfma_f32_16x16x32_bf16(ah[mi], bl[ni], acc[mi][ni], 0, 0, 0);
#pragma unroll
            for (int mi = 0; mi < 4; ++mi)
#pragma unroll
                for (int ni = 0; ni < 4; ++ni)
                    acc[mi][ni] = __builtin_amdgcn_mfma_f32_16x16x32_bf16(al[mi], bh[ni], acc[mi][ni], 0, 0, 0);
        }
    }

    float bv[4];
#pragma unroll
    for (int ni = 0; ni < 4; ++ni) bv[ni] = bias ? bias[bN + wn + ni * 16 + m16] : 0.f;
    float vv[4] = {}, ls[4] = {};
    if constexpr (EPI == 3 || DOT == 1) {
#pragma unroll
        for (int ni = 0; ni < 4; ++ni) {
            vv[ni] = vvec[bN + wn + ni * 16 + m16];
            if constexpr (EPI == 3) ls[ni] = logsig(vv[ni]);
        }
    }
    float ds[4][4] = {};

#pragma unroll
    for (int mi = 0; mi < 4; ++mi) {
#pragma unroll
        for (int ni = 0; ni < 4; ++ni) {
#pragma unroll
            for (int r = 0; r < 4; ++r) {
                // C/D: col = lane&15, row = (lane>>4)*4 + reg  [m89-verified]
                const long grow = bM + wm + mi * 16 + (kq << 2) + r;
                const long gcol = bN + wn + ni * 16 + m16;
                const long idx  = grow * ldC + gcol;
                float v = acc[mi][ni][r] + bv[ni];
                if constexpr (EPI == 1) v *= Q[idx];
                if constexpr (EPI == 2)
                    v = 0.5f * v * (1.f + tanhf(0.7978845608028654f * (v + 0.044715f * v * v * v)));
                if constexpr (EPI == 3) v = expf(8.f * sigm(v) * ls[ni]);
                if constexpr (EPI == 4) {
                    const float a = Q[idx];
                    v = sqrtf(fmaxf(1.f - a * a, 0.f)) * sigm(v);
                }
                if constexpr (ACC) v += C[idx];
                if constexpr (DOT) ds[mi][r] += v * vv[ni];
                if constexpr (ST == 1) Chi[idx] = bf16_rne(v);
                else C[idx] = v;
            }
        }
    }

    if constexpr (DOT) {
#pragma unroll
        for (int mi = 0; mi < 4; ++mi)
#pragma unroll
            for (int r = 0; r < 4; ++r) {
                float s = ds[mi][r];
                s += __shfl_xor(s, 1);
                s += __shfl_xor(s, 2);
                s += __shfl_xor(s, 4);
                s += __shfl_xor(s, 8);
                if (m16 == 0)
                    atomicAdd(&dacc[bM + wm + mi * 16 + (kq << 2) + r], s);
            }
    }
}

// ---------------------------------------------------------------------------
// gemm8v2 — derived-waits 256x256 pipeline (T3+T4+T5).  Pre-split bf16
// planes in HBM, 512 thr = 8 waves (2M x 4N), BK=32, LDS double-buffer.
// Retirement proof drives the schedule: B-frags + A-stripe-q of buf p are
// register-landed by phase q's lgkmcnt(0)+barrier, so stage-for-t+2 spreads
// as {B planes @ phase 1, wave's A band @ phase min(stripe+1,3)}.  Per-wave
// counted drain vmcnt(8 NP3 / 4 NP1) at tile end — never 0 mid-loop.
// Next-phase A-frags ds_read-issued during current phase's MFMA cluster
// (register dbuf, static idx).  setprio(1) around MFMA.  XCD swizzle.
// MFMA order per acc element (hh,hl,lh per K-tile) == gemm_sp -> numerics
// bit-identical.  EPI: 0 none, 1 v*=Q, 2 gelu, 3 a-epi, 4 q-epi.
// ---------------------------------------------------------------------------
template <int NPROD, int EPI, int ACC, int ST, int DOT>
__global__ __launch_bounds__(512, 2) void gemm8v2(
    const u16* __restrict__ Ah, const u16* __restrict__ Al,
    const u16* __restrict__ Bh, const u16* __restrict__ Bl,
    const float* __restrict__ bias,
    float* C, u16* Chi, const float* __restrict__ Q,
    const float* __restrict__ vvec, float* dacc,
    long ldA, long ldB, long ldC, int K)
{
    constexpr int NPL = (NPROD == 3) ? 4 : 2;   // [0]=Ah [1]=Bh [2]=Al [3]=Bl
    __shared__ __align__(16) u16 lds[2][NPL][8192];

    const int tid  = threadIdx.x;
    const int lane = tid & 63;
    const int wid  = tid >> 6;      // 0..7
    const int wr   = wid >> 2;      // 0..1 (M)
    const int wc   = wid & 3;       // 0..3 (N)
    const int m16  = lane & 15;
    const int kq   = lane >> 4;
    const int bst  = wid & 3;       // wave's A-band stripe

    // XCD-bijective swizzle (requires nwg % 8 == 0; grids here are 256)
    const int nbx = gridDim.x;
    const int lin = blockIdx.y * nbx + blockIdx.x;
    const int nwg = nbx * gridDim.y;
    int bx = blockIdx.x, by = blockIdx.y;
    if ((nwg & 7) == 0) {
        const int s = (lin & 7) * (nwg >> 3) + (lin >> 3);
        bx = s % nbx;
        by = s / nbx;
    }
    const long bM = (long)by << 8;
    const long bN = (long)bx << 8;

    // staging: wave wid owns rows [wid*32, wid*32+32) of each plane.
    const int  drow = (wid << 5) + (lane >> 2);
    const int  qsrc = (((lane & 3) ^ ((lane >> 3) & 3)) << 3);
    const u16* gA0  = Ah + (bM + drow) * ldA + qsrc;
    const u16* gA1  = gA0 + (ldA << 4);
    const u16* gB0  = Bh + (bN + drow) * ldB + qsrc;
    const u16* gB1  = gB0 + (ldB << 4);
    const u16* gAl0 = (NPROD == 3 ? Al : Ah) + (bM + drow) * ldA + qsrc;
    const u16* gAl1 = gAl0 + (ldA << 4);
    const u16* gBl0 = (NPROD == 3 ? Bl : Bh) + (bN + drow) * ldB + qsrc;
    const u16* gBl1 = gBl0 + (ldB << 4);

    const int lwb = wid << 10;                        // wid*32 rows * 32 u16
    const int kr  = ((kq ^ ((m16 >> 1) & 3)) << 3);   // phys chunk on read
    const int NT  = K >> 5;

    auto stageA = [&](int buf, int t) {
        const long k0 = (long)t << 5;
        gld16(gA0 + k0, &lds[buf][0][lwb]);
        gld16(gA1 + k0, &lds[buf][0][lwb + 512]);
        if constexpr (NPROD == 3) {
            gld16(gAl0 + k0, &lds[buf][2][lwb]);
            gld16(gAl1 + k0, &lds[buf][2][lwb + 512]);
        }
    };
    auto stageB = [&](int buf, int t) {
        const long k0 = (long)t << 5;
        gld16(gB0 + k0, &lds[buf][1][lwb]);
        gld16(gB1 + k0, &lds[buf][1][lwb + 512]);
        if constexpr (NPROD == 3) {
            gld16(gBl0 + k0, &lds[buf][3][lwb]);
            gld16(gBl1 + k0, &lds[buf][3][lwb + 512]);
        }
    };

    floatx4 acc[8][4] = {};
    short8 bhr[4], blr[4];
    short8 fa[2][4];    // register-dbuf A frags: [phase&1][ah0,ah1,al0,al1]

    // prologue: burst-stage tiles 0 and 1
    stageA(0, 0); stageB(0, 0);
    stageA(1, 1); stageB(1, 1);
    if constexpr (NPROD == 3) vmwait8(); else vmwait4();
    barr();

    const int arow = (wr << 7) + m16;
    const int brow = (wc << 6) + m16;

#pragma unroll 1
    for (int t = 0; t < NT; ++t) {
        const int p  = t & 1;
        const bool pf = (t + 2 < NT);

        // tile top: B frags (held all tile) + stripe-0 A frags
#pragma unroll
        for (int ni = 0; ni < 4; ++ni) {
            const int rb = (brow + (ni << 4)) << 5;
            bhr[ni] = *(const short8*)&lds[p][1][rb + kr];
            if constexpr (NPROD == 3) blr[ni] = *(const short8*)&lds[p][3][rb + kr];
        }
        fa[0][0] = *(const short8*)&lds[p][0][(arow << 5) + kr];
        fa[0][1] = *(const short8*)&lds[p][0][((arow + 16) << 5) + kr];
        if constexpr (NPROD == 3) {
            fa[0][2] = *(const short8*)&lds[p][2][(arow << 5) + kr];
            fa[0][3] = *(const short8*)&lds[p][2][((arow + 16) << 5) + kr];
        }

#pragma unroll
        for (int q = 0; q < 4; ++q) {
            const int cur = q & 1;
            const int nxt = cur ^ 1;
            if (q < 3) {    // issue next-phase frag reads (overlap with MFMA)
                const int r0 = arow + ((q + 1) << 5);
                fa[nxt][0] = *(const short8*)&lds[p][0][(r0 << 5) + kr];
                fa[nxt][1] = *(const short8*)&lds[p][0][((r0 + 16) << 5) + kr];
                if constexpr (NPROD == 3) {
                    fa[nxt][2] = *(const short8*)&lds[p][2][(r0 << 5) + kr];
                    fa[nxt][3] = *(const short8*)&lds[p][2][((r0 + 16) << 5) + kr];
                }
            }
            if (pf) {       // spread stage for t+2 into retired regions
                if (q == 1) stageB(p, t + 2);
                if (q == (bst >= 2 ? 3 : bst + 1)) stageA(p, t + 2);
            }
            __builtin_amdgcn_s_setprio(1);
#pragma unroll
            for (int ni = 0; ni < 4; ++ni) {
                acc[2 * q][ni]     = __builtin_amdgcn_mfma_f32_16x16x32_bf16(fa[cur][0], bhr[ni], acc[2 * q][ni], 0, 0, 0);
                acc[2 * q + 1][ni] = __builtin_amdgcn_mfma_f32_16x16x32_bf16(fa[cur][1], bhr[ni], acc[2 * q + 1][ni], 0, 0, 0);
            }
            if constexpr (NPROD == 3) {
#pragma unroll
                for (int ni = 0; ni < 4; ++ni) {
                    acc[2 * q][ni]     = __builtin_amdgcn_mfma_f32_16x16x32_bf16(fa[cur][0], blr[ni], acc[2 * q][ni], 0, 0, 0);
                    acc[2 * q + 1][ni] = __builtin_amdgcn_mfma_f32_16x16x32_bf16(fa[cur][1], blr[ni], acc[2 * q + 1][ni], 0, 0, 0);
                }
#pragma unroll
                for (int ni = 0; ni < 4; ++ni) {
                    acc[2 * q][ni]     = __builtin_amdgcn_mfma_f32_16x16x32_bf16(fa[cur][2], bhr[ni], acc[2 * q][ni], 0, 0, 0);
                    acc[2 * q + 1][ni] = __builtin_amdgcn_mfma_f32_16x16x32_bf16(fa[cur][3], bhr[ni], acc[2 * q + 1][ni], 0, 0, 0);
                }
            }
            __builtin_amdgcn_s_setprio(0);
            lgwait0();                      // all this-phase ds_reads landed
            if (q == 3) {                   // counted drain: t+1's loads done
                if (pf) { if constexpr (NPROD == 3) vmwait8(); else vmwait4(); }
                else vmwait0();
            }
            barr();
        }
    }

    float bv[4];
#pragma unroll
    for (int ni = 0; ni < 4; ++ni) bv[ni] = bias ? bias[bN + (wc << 6) + (ni << 4) + m16] : 0.f;
    float vv[4] = {}, ls[4] = {};
    if constexpr (EPI == 3 || DOT == 1) {
#pragma unroll
        for (int ni = 0; ni < 4; ++ni) {
            vv[ni] = vvec[bN + (wc << 6) + (ni << 4) + m16];
            if constexpr (EPI == 3) ls[ni] = logsig(vv[ni]);
        }
    }
    float ds[8][4] = {};

#pragma unroll
    for (int mi = 0; mi < 8; ++mi) {
#pragma unroll
        for (int ni = 0; ni < 4; ++ni) {
#pragma unroll
            for (int r = 0; r < 4; ++r) {
                // C/D: col = lane&15, row = (lane>>4)*4 + reg  [m89-verified]
                const long grow = bM + (wr << 7) + (mi << 4) + (kq << 2) + r;
                const long gcol = bN + (wc << 6) + (ni << 4) + m16;
                const long idx  = grow * ldC + gcol;
                float v = acc[mi][ni][r] + bv[ni];
                if constexpr (EPI == 1) v *= Q[idx];
                if constexpr (EPI == 2)
                    v = 0.5f * v * (1.f + tanhf(0.7978845608028654f * (v + 0.044715f * v * v * v)));
                if constexpr (EPI == 3) v = expf(8.f * sigm(v) * ls[ni]);
                if constexpr (EPI == 4) {
                    const float a = Q[idx];
                    v = sqrtf(fmaxf(1.f - a * a, 0.f)) * sigm(v);
                }
                if constexpr (ACC) v += C[idx];
                if constexpr (DOT) ds[mi][r] += v * vv[ni];
                if constexpr (ST == 1) Chi[idx] = bf16_rne(v);
                else C[idx] = v;
            }
        }
    }

    if constexpr (DOT) {
#pragma unroll
        for (int mi = 0; mi < 8; ++mi)
#pragma unroll
            for (int r = 0; r < 4; ++r) {
                float s = ds[mi][r];
                s += __shfl_xor(s, 1);
                s += __shfl_xor(s, 2);
                s += __shfl_xor(s, 4);
                s += __shfl_xor(s, 8);
                if (m16 == 0)
                    atomicAdd(&dacc[bM + (wr << 7) + (mi << 4) + (kq << 2) + r], s);
            }
    }
}

// ---------------------------------------------------------------------------
// fp32 -> bf16 hi(/lo) planes.  One block per row, 2048 cols.
template <int HASLO>
__global__ __launch_bounds__(256) void split_kernel(
    const float* __restrict__ src, long lds,
    u16* __restrict__ hi, u16* __restrict__ lo, long ldd)
{
    const long r = blockIdx.x;
    const int  c = threadIdx.x << 3;
    const float* p = src + r * lds + c;
    const float4 a = *(const float4*)p;
    const float4 b = *(const float4*)(p + 4);
    const float v[8] = {a.x, a.y, a.z, a.w, b.x, b.y, b.z, b.w};
    short8 h8, l8;
#pragma unroll
    for (int j = 0; j < 8; ++j) {
        const u16 hh = bf16_rne(v[j]);
        h8[j] = (short)hh;
        if constexpr (HASLO) l8[j] = (short)bf16_rne(v[j] - bf16_to_f(hh));
    }
    *(short8*)&hi[r * ldd + c] = h8;
    if constexpr (HASLO) *(short8*)&lo[r * ldd + c] = l8;
}

__global__ __launch_bounds__(256) void zb2init_kernel(
    float* __restrict__ zb2, const float* __restrict__ zc2)
{
    zb2[blockIdx.x * 256 + threadIdx.x] = zc2[0];
}

// ---------------------------------------------------------------------------
// (fallback path B only)
__global__ __launch_bounds__(256) void aq_kernel(
    float* za, float* zg, const float* __restrict__ lam)
{
    const long i = ((long)blockIdx.x * 256 + threadIdx.x) * 4;
    const int  c = (int)(i & 2047);
    const float4 zav = *(const float4*)(za + i);
    const float4 zgv = *(const float4*)(zg + i);
    const float4 lmv = *(const float4*)(lam + c);
    float4 av, qv;
    const float zaa[4] = {zav.x, zav.y, zav.z, zav.w};
    const float zga[4] = {zgv.x, zgv.y, zgv.z, zgv.w};
    const float lma[4] = {lmv.x, lmv.y, lmv.z, lmv.w};
    float aa[4], qa[4];
#pragma unroll
    for (int j = 0; j < 4; ++j) {
        const float r  = sigm(zaa[j]);
        const float g  = sigm(zga[j]);
        const float la = 8.f * r * logsig(lma[j]);
        aa[j] = expf(la);
        qa[j] = sqrtf(fmaxf(1.f - expf(2.f * la), 0.f)) * g;
    }
    av.x = aa[0]; av.y = aa[1]; av.z = aa[2]; av.w = aa[3];
    qv.x = qa[0]; qv.y = qa[1]; qv.z = qa[2]; qv.w = qa[3];
    *(float4*)(za + i) = av;
    *(float4*)(zg + i) = qv;
}

// ---------------------------------------------------------------------------
// chunked scan over S (stride 2048): h_t = a_t h_{t-1} + b_t
__global__ __launch_bounds__(256) void scan_partial(
    const float* __restrict__ A, const float* __restrict__ B,
    float* __restrict__ Aagg, float* __restrict__ Bagg)
{
    const int c = blockIdx.x * 256 + threadIdx.x;
    const int p = blockIdx.y;
    const long base = (long)p * SCAN_L * 2048 + c;
    float Ar = 1.f, Br = 0.f;
    for (int t = 0; t < SCAN_L; ++t) {
        const float at = A[base + (long)t * 2048];
        const float bt = B[base + (long)t * 2048];
        Ar *= at;
        Br = Br * at + bt;
    }
    Aagg[p * 2048 + c] = Ar;
    Bagg[p * 2048 + c] = Br;
}

__global__ __launch_bounds__(256) void scan_combine(
    const float* __restrict__ Aagg, const float* __restrict__ Bagg,
    float* __restrict__ Hini)
{
    const int c = blockIdx.x * 256 + threadIdx.x;
    float h = 0.f;
    for (int p = 0; p < SCAN_P; ++p) {
        Hini[p * 2048 + c] = h;
        h = Aagg[p * 2048 + c] * h + Bagg[p * 2048 + c];
    }
}

// reads a (A) and b (B), writes h fp32 over A; optionally also bf16-hi plane
__global__ __launch_bounds__(256) void scan_final(
    float* A, const float* __restrict__ B, const float* __restrict__ Hini,
    u16* __restrict__ Hhi)
{
    const int c = blockIdx.x * 256 + threadIdx.x;
    const int p = blockIdx.y;
    const long base = (long)p * SCAN_L * 2048 + c;
    float h = Hini[p * 2048 + c];
    for (int t = 0; t < SCAN_L; ++t) {
        const long idx = base + (long)t * 2048;
        h = A[idx] * h + B[idx];
        A[idx] = h;
        if (Hhi) Hhi[idx] = bf16_rne(h);
    }
}

// ---------------------------------------------------------------------------
// v[j] = sum_d W[d,j] * w[d]   (chunked partials, then reduce)
__global__ __launch_bounds__(256) void vpart_kernel(
    const float* __restrict__ W, const float* __restrict__ w,
    float* __restrict__ part, long ldW, int dchunk)
{
    const int j  = blockIdx.x * 256 + threadIdx.x;
    const int d0 = blockIdx.y * dchunk;
    float s = 0.f;
    for (int d = 0; d < dchunk; ++d) s += W[(long)(d0 + d) * ldW + j] * w[d0 + d];
    part[(long)blockIdx.y * ldW + j] = s;
}

__global__ __launch_bounds__(256) void vreduce_kernel(
    const float* __restrict__ part, float* __restrict__ v, long ldW, int nch)
{
    const int j = blockIdx.x * 256 + threadIdx.x;
    float s = 0.f;
    for (int c = 0; c < nch; ++c) s += part[(long)c * ldW + j];
    v[j] = s;
}

__global__ __launch_bounds__(256) void dotc_kernel(
    const float* __restrict__ a, const float* __restrict__ b,
    const float* __restrict__ bias1, float* __restrict__ out)
{
    __shared__ float red[4];
    const int tid = threadIdx.x, lane = tid & 63, wid = tid >> 6;
    float s = 0.f;
    for (int d = tid; d < 2048; d += 256) s += a[d] * b[d];
#pragma unroll
    for (int off = 32; off > 0; off >>= 1) s += __shfl_down(s, off);
    if (lane == 0) red[wid] = s;
    __syncthreads();
    if (tid == 0) out[0] = red[0] + red[1] + red[2] + red[3] + bias1[0];
}

// ---------------------------------------------------------------------------
// (path B only)
template <int INIT>
__global__ __launch_bounds__(256) void zacc_kernel(
    const u16* __restrict__ uHi, const u16* __restrict__ uLo,
    const float* __restrict__ v2s, const float* __restrict__ zc,
    float* __restrict__ zb, int L)
{
    __shared__ float red[4];
    const int tid = threadIdx.x, lane = tid & 63, wid = tid >> 6;
    const long s = blockIdx.x;
    const long base = s * (long)L;
    float dot = 0.f;
    for (int f = tid; f < L; f += 256)
        dot += (bf16_to_f(uHi[base + f]) + bf16_to_f(uLo[base + f])) * v2s[f];
#pragma unroll
    for (int off = 32; off > 0; off >>= 1) dot += __shfl_down(dot, off);
    if (lane == 0) red[wid] = dot;
    __syncthreads();
    if (tid == 0) {
        const float t = red[0] + red[1] + red[2] + red[3];
        zb[s] = INIT ? (zc[0] + t) : (zb[s] + t);
    }
}

// ---------------------------------------------------------------------------
// gate1 (path B): fp32 x1 in place over res1
__global__ __launch_bounds__(256) void gate1_kernel(
    const float* __restrict__ x, float* res1x1,
    const float* __restrict__ h,
    const float* __restrict__ v1, const float* __restrict__ zc1,
    const float* __restrict__ u1,
    const float* __restrict__ nw, const float* __restrict__ nb)
{
    __shared__ float red[4];
    const int tid = threadIdx.x, lane = tid & 63, wid = tid >> 6;
    const long s = blockIdx.x;
    const long base = s * 2048;

    float dot = 0.f;
#pragma unroll
    for (int k = 0; k < 8; ++k) {
        const int d = tid + (k << 8);
        dot += h[base + d] * v1[d];
    }
#pragma unroll
    for (int off = 32; off > 0; off >>= 1) dot += __shfl_down(dot, off);
    if (lane == 0) red[wid] = dot;
    __syncthreads();
    const float z = red[0] + red[1] + red[2] + red[3] + zc1[0];
    __syncthreads();

    const float g = (u1[s] < sigm(z)) ? 1.f : 0.f;

    float yv[8];
    float ss = 0.f;
#pragma unroll
    for (int k = 0; k < 8; ++k) {
        const int d = tid + (k << 8);
        const float y = x[base + d] + g * res1x1[base + d];
        yv[k] = y;
        ss += y * y;
    }
#pragma unroll
    for (int off = 32; off > 0; off >>= 1) ss += __shfl_down(ss, off);
    if (lane == 0) red[wid] = ss;
    __syncthreads();
    const float inv = rsqrtf((red[0] + red[1] + red[2] + red[3]) * (1.f / 2048.f) + 1e-6f);

#pragma unroll
    for (int k = 0; k < 8; ++k) {
        const int d = tid + (k << 8);
        res1x1[base + d] = yv[k] * inv * nw[d] + nb[d];
    }
}

// gate1 (path A): writes x1 as row-interleaved bf16 hi/lo split, in place
__global__ __launch_bounds__(256) void gate1s_kernel(
    const float* __restrict__ x, float* res1x1,
    const float* __restrict__ h,
    const float* __restrict__ v1, const float* __restrict__ zc1,
    const float* __restrict__ u1,
    const float* __restrict__ nw, const float* __restrict__ nb)
{
    __shared__ float red[4];
    const int tid = threadIdx.x, lane = tid & 63, wid = tid >> 6;
    const long s = blockIdx.x;
    const long base = s * 2048;

    float dot = 0.f;
#pragma unroll
    for (int k = 0; k < 8; ++k) {
        const int d = tid + (k << 8);
        dot += h[base + d] * v1[d];
    }
#pragma unroll
    for (int off = 32; off > 0; off >>= 1) dot += __shfl_down(dot, off);
    if (lane == 0) red[wid] = dot;
    __syncthreads();
    const float z = red[0] + red[1] + red[2] + red[3] + zc1[0];
    __syncthreads();

    const float g = (u1[s] < sigm(z)) ? 1.f : 0.f;

    float yv[8];
    float ss = 0.f;
#pragma unroll
    for (int k = 0; k < 8; ++k) {
        const int d = tid + (k << 8);
        const float y = x[base + d] + g * res1x1[base + d];
        yv[k] = y;
        ss += y * y;
    }
#pragma unroll
    for (int off = 32; off > 0; off >>= 1) ss += __shfl_down(ss, off);
    if (lane == 0) red[wid] = ss;
    __syncthreads();
    const float inv = rsqrtf((red[0] + red[1] + red[2] + red[3]) * (1.f / 2048.f) + 1e-6f);

    u16* xs = (u16*)res1x1;
    const long sb = s * 4096;
#pragma unroll
    for (int k = 0; k < 8; ++k) {
        const int d = tid + (k << 8);
        const float o = yv[k] * inv * nw[d] + nb[d];
        const u16 hh = bf16_rne(o);
        xs[sb + d] = hh;
        xs[sb + 2048 + d] = bf16_rne(o - bf16_to_f(hh));
    }
}

// gate2 (path B)
__global__ __launch_bounds__(256) void gate2_kernel(
    float* x1out, const float* __restrict__ res2,
    const float* __restrict__ zb2, const float* __restrict__ u2,
    const float* __restrict__ nw, const float* __restrict__ nb)
{
    __shared__ float red[4];
    const int tid = threadIdx.x, lane = tid & 63, wid = tid >> 6;
    const long s = blockIdx.x;
    const long base = s * 2048;

    const float g = (u2[s] < sigm(zb2[s])) ? 1.f : 0.f;

    float yv[8];
    float ss = 0.f;
#pragma unroll
    for (int k = 0; k < 8; ++k) {
        const int d = tid + (k << 8);
        const float y = x1out[base + d] + g * res2[base + d];
        yv[k] = y;
        ss += y * y;
    }
#pragma unroll
    for (int off = 32; off > 0; off >>= 1) ss += __shfl_down(ss, off);
    if (lane == 0) red[wid] = ss;
    __syncthreads();
    const float inv = rsqrtf((red[0] + red[1] + red[2] + red[3]) * (1.f / 2048.f) + 1e-6f);

#pragma unroll
    for (int k = 0; k < 8; ++k) {
        const int d = tid + (k << 8);
        x1out[base + d] = yv[k] * inv * nw[d] + nb[d];
    }
}

// gate2 (path A): x1 reconstructed from hi+lo split; fp32 out in place.
__global__ __launch_bounds__(256) void gate2s_kernel(
    float* x1out, const float* __restrict__ res2,
    const float* __restrict__ zb2, const float* __restrict__ u2,
    const float* __restrict__ nw, const float* __restrict__ nb)
{
    __shared__ float red[4];
    const int tid = threadIdx.x, lane = tid & 63, wid = tid >> 6;
    const long s = blockIdx.x;
    const long base = s * 2048;
    const u16* xs = (const u16*)x1out;
    const long sb = s * 4096;

    const float g = (u2[s] < sigm(zb2[s])) ? 1.f : 0.f;

    float yv[8];
    float ss = 0.f;
#pragma unroll
    for (int k = 0; k < 8; ++k) {
        const int d = tid + (k << 8);
        const float x1 = bf16_to_f(xs[sb + d]) + bf16_to_f(xs[sb + 2048 + d]);
        const float y = x1 + g * res2[base + d];
        yv[k] = y;
        ss += y * y;
    }
#pragma unroll
    for (int off = 32; off > 0; off >>= 1) ss += __shfl_down(ss, off);
    if (lane == 0) red[wid] = ss;
    __syncthreads();
    const float inv = rsqrtf((red[0] + red[1] + red[2] + red[3]) * (1.f / 2048.f) + 1e-6f);

#pragma unroll
    for (int k = 0; k < 8; ++k) {
        const int d = tid + (k << 8);
        x1out[base + d] = yv[k] * inv * nw[d] + nb[d];
    }
}

// ---------------------------------------------------------------------------
extern "C" void kernel_launch(void* const* d_in, const int* in_sizes, int n_in,
                              void* d_out, int out_size, void* d_ws, size_t ws_size,
                              hipStream_t stream)
{
    const float* x     = (const float*)d_in[0];
    const float* W_in  = (const float*)d_in[1];
    const float* b_in  = (const float*)d_in[2];
    const float* W_a   = (const float*)d_in[3];
    const float* b_a   = (const float*)d_in[4];
    const float* W_g   = (const float*)d_in[5];
    const float* b_g   = (const float*)d_in[6];
    const float* lam   = (const float*)d_in[7];
    const float* W_out = (const float*)d_in[8];
    const float* b_out = (const float*)d_in[9];
    const float* w1    = (const float*)d_in[10];
    const float* fb1   = (const float*)d_in[11];
    const float* w2    = (const float*)d_in[12];
    const float* fb2   = (const float*)d_in[13];
    const float* a1w   = (const float*)d_in[14];
    const float* a1b   = (const float*)d_in[15];
    const float* a2w   = (const float*)d_in[16];
    const float* a2b   = (const float*)d_in[17];
    const float* n1w   = (const float*)d_in[18];
    const float* n1b   = (const float*)d_in[19];
    const float* n2w   = (const float*)d_in[20];
    const float* n2b   = (const float*)d_in[21];
    const float* u1    = (const float*)d_in[22];
    const float* u2    = (const float*)d_in[23];
    (void)in_sizes; (void)n_in; (void)out_size;

    float* dob = (float*)d_out;          // 64 MiB fp32 scratch until final write

    char* ws = (char*)d_ws;
    size_t o = 0;
    auto take = [&](size_t bytes) -> char* {
        char* p = ws + o;
        o += (bytes + 255) & ~(size_t)255;
        return p;
    };

    float* Aagg = (float*)take((size_t)SCAN_P * 2048 * 4);
    float* Bagg = (float*)take((size_t)SCAN_P * 2048 * 4);
    float* Hini = (float*)take((size_t)SCAN_P * 2048 * 4);
    float* v1   = (float*)take(2048 * 4);
    float* v2   = (float*)take(8192 * 4);
    float* vp   = (float*)take(16 * 8192 * 4);
    float* zc1  = (float*)take(256);
    float* zc2  = (float*)take(256);
    float* zb2  = (float*)take(8192 * 4);

    float* slabA = (float*)take(64ull << 20);
    const bool pathA = ws_size >= o + (64ull << 20);
    float* slabB = nullptr;
    float* res2b = nullptr;
    float* slabW = nullptr;   // optional 16 MB weight-split slab (tier A2)
    if (pathA) {
        slabB = (float*)take(64ull << 20);
        if (ws_size >= o + (16ull << 20)) slabW = (float*)take(16ull << 20);
    } else {
        res2b = (float*)take(16ull << 20);
    }
    if (o > ws_size) return;  // diagnostic: absmax == max|ref| signature

    const dim3 blk(256);
    const dim3 blk8(512);
    const dim3 g8(8, 32);     // 256x256 tiles over [8192 x 2048]

    // gate-logit vectors (exact fp32 path; gates never see GEMM error)
    vpart_kernel<<<dim3(8, 16), blk, 0, stream>>>(W_out, a1w, vp, 2048, 128);
    vreduce_kernel<<<8, blk, 0, stream>>>(vp, v1, 2048, 16);
    vpart_kernel<<<dim3(32, 16), blk, 0, stream>>>(w2, a2w, vp, 8192, 128);
    vreduce_kernel<<<32, blk, 0, stream>>>(vp, v2, 8192, 16);
    dotc_kernel<<<1, blk, 0, stream>>>(b_out, a1w, a1b, zc1);
    dotc_kernel<<<1, blk, 0, stream>>>(fb2, a2w, a2b, zc2);

    if (pathA) {
        // ---- phase 1: pre-split A(x) ----
        u16* const xh = (u16*)slabA;
        u16* const xl = xh + (1u << 24);
        split_kernel<1><<<8192, blk, 0, stream>>>(x, 2048, xh, xl, 2048);

        if (slabW) {
            // weights hi/lo split sequentially into slabW -> full-DMA gemm8v2
            u16* const wH = (u16*)slabW;
            u16* const wL = wH + (1u << 22);
            // a = exp(8*sigm(za)*logsig(lam)) -> slabB   (EPI=3)
            split_kernel<1><<<2048, blk, 0, stream>>>(W_a, 2048, wH, wL, 2048);
            gemm8v2<3, 3, 0, 0, 0><<<g8, blk8, 0, stream>>>(
                xh, xl, wH, wL, b_a, slabB, nullptr, nullptr, lam, nullptr,
                2048, 2048, 2048, 2048);
            // q = sqrt(1-a^2)*sigm(zg) -> dob            (EPI=4, Q=a)
            split_kernel<1><<<2048, blk, 0, stream>>>(W_g, 2048, wH, wL, 2048);
            gemm8v2<3, 4, 0, 0, 0><<<g8, blk8, 0, stream>>>(
                xh, xl, wH, wL, b_g, dob, nullptr, slabB, nullptr, nullptr,
                2048, 2048, 2048, 2048);
            // b = q * (x@W_in^T + b_in) in place over dob (EPI=1, Q=C=dob)
            split_kernel<1><<<2048, blk, 0, stream>>>(W_in, 2048, wH, wL, 2048);
            gemm8v2<3, 1, 0, 0, 0><<<g8, blk8, 0, stream>>>(
                xh, xl, wH, wL, b_in, dob, nullptr, dob, nullptr, nullptr,
                2048, 2048, 2048, 2048);
        } else {
            gemm_sp<3, 0, 3, 0, 0, 0><<<dim3(16, 64), blk, 0, stream>>>(
                xh, xl, nullptr, nullptr, W_a, b_a, slabB, nullptr, nullptr, lam, nullptr,
                2048, 2048, 2048, 2048);
            gemm_sp<3, 0, 4, 0, 0, 0><<<dim3(16, 64), blk, 0, stream>>>(
                xh, xl, nullptr, nullptr, W_g, b_g, dob, nullptr, slabB, nullptr, nullptr,
                2048, 2048, 2048, 2048);
            gemm_sp<3, 0, 1, 0, 0, 0><<<dim3(16, 64), blk, 0, stream>>>(
                xh, xl, nullptr, nullptr, W_in, b_in, dob, nullptr, dob, nullptr, nullptr,
                2048, 2048, 2048, 2048);
        }

        // scan: a(slabB), b(dob) -> h fp32 over slabB, bf16-hi plane -> slabA
        u16* const hH = (u16*)slabA;                   // xh/xl dead after b-GEMM
        scan_partial<<<dim3(8, SCAN_P), blk, 0, stream>>>(slabB, dob, Aagg, Bagg);
        scan_combine<<<8, blk, 0, stream>>>(Aagg, Bagg, Hini);
        scan_final<<<dim3(8, SCAN_P), blk, 0, stream>>>(slabB, dob, Hini, hH);

        // ---- res1 = hHi @ W_outHi^T + b_out (NPROD=1) ----
        u16* const woH = hH + (1u << 24);              // [32:40MB)
        split_kernel<0><<<2048, blk, 0, stream>>>(W_out, 2048, woH, nullptr, 2048);
        gemm8v2<1, 0, 0, 0, 0><<<g8, blk8, 0, stream>>>(
            hH, nullptr, woH, nullptr, b_out, dob, nullptr, nullptr, nullptr, nullptr,
            2048, 2048, 2048, 2048);

        // gate1 + rmsnorm -> x1 split (hi/lo interleaved) in place over dob
        gate1s_kernel<<<8192, blk, 0, stream>>>(x, dob, slabB, v1, zc1, u1, n1w, n1b);

        // zb2 = zc2 (u-GEMM epilogues atomically accumulate the exact dot)
        zb2init_kernel<<<32, blk, 0, stream>>>(zb2, zc2);

        // ---- FFN over 4 F-chunks; u stored bf16-hi only; res2 -> slabB ----
        u16* const uH  = (u16*)slabA;                  // [0:32MB)  (hH dead)
        u16* const w1H = uH + (1u << 24);              // [32:40MB) (woH dead)
        u16* const w1L = w1H + (1u << 22);             // [40:48MB)
        u16* const w2H = w1H + (1u << 23);             // [48:56MB)
        u16* const x1h = (u16*)dob;                    // ldA=4096, lo at +2048
        for (int c = 0; c < 4; ++c) {
            const long f0 = (long)c << 11;
            split_kernel<1><<<2048, blk, 0, stream>>>(w1 + f0 * 2048, 2048, w1H, w1L, 2048);
            split_kernel<0><<<2048, blk, 0, stream>>>(w2 + f0, 8192, w2H, nullptr, 2048);
            // u = gelu(x1@w1c^T + b1c); store hi; fused zb2 += u . v2c
            gemm8v2<3, 2, 0, 1, 1><<<g8, blk8, 0, stream>>>(
                x1h, x1h + 2048, w1H, w1L, fb1 + f0, nullptr, uH, nullptr,
                v2 + f0, zb2, 4096, 2048, 2048, 2048);
            if (c == 0)
                gemm8v2<1, 0, 0, 0, 0><<<g8, blk8, 0, stream>>>(
                    uH, nullptr, w2H, nullptr, fb2, slabB, nullptr, nullptr, nullptr, nullptr,
                    2048, 2048, 2048, 2048);
            else
                gemm8v2<1, 0, 1, 0, 0><<<g8, blk8, 0, stream>>>(
                    uH, nullptr, w2H, nullptr, nullptr, slabB, nullptr, nullptr, nullptr, nullptr,
                    2048, 2048, 2048, 2048);
        }
        gate2s_kernel<<<8192, blk, 0, stream>>>(dob, slabB, zb2, u2, n2w, n2b);
    } else {
        // ---------------- fallback: original path B, verbatim ----------------
        u16* uHi = (u16*)slabA;
        u16* uLo = uHi + (1u << 24);

        gemm_f32<0, 3, 0, 0, 0><<<dim3(16, 64), blk, 0, stream>>>(
            x, nullptr, W_a, b_a, slabA, nullptr, nullptr, nullptr, 2048, 2048, 2048, 2048);
        gemm_f32<0, 3, 0, 0, 0><<<dim3(16, 64), blk, 0, stream>>>(
            x, nullptr, W_g, b_g, dob, nullptr, nullptr, nullptr, 2048, 2048, 2048, 2048);
        aq_kernel<<<16384, blk, 0, stream>>>(slabA, dob, lam);
        gemm_f32<0, 3, 1, 0, 0><<<dim3(16, 64), blk, 0, stream>>>(
            x, nullptr, W_in, b_in, dob, nullptr, nullptr, dob, 2048, 2048, 2048, 2048);
        scan_partial<<<dim3(8, SCAN_P), blk, 0, stream>>>(slabA, dob, Aagg, Bagg);
        scan_combine<<<8, blk, 0, stream>>>(Aagg, Bagg, Hini);
        scan_final<<<dim3(8, SCAN_P), blk, 0, stream>>>(slabA, dob, Hini, nullptr);
        gemm_f32<0, 1, 0, 0, 0><<<dim3(16, 64), blk, 0, stream>>>(
            slabA, nullptr, W_out, b_out, dob, nullptr, nullptr, nullptr, 2048, 2048, 2048, 2048);
        gate1_kernel<<<8192, blk, 0, stream>>>(x, dob, slabA, v1, zc1, u1, n1w, n1b);
        for (int rb = 0; rb < 4; ++rb) {
            const long roff = (long)rb * 2048;
            gemm_f32<0, 3, 2, 0, 1><<<dim3(64, 16), blk, 0, stream>>>(
                dob + roff * 2048, nullptr, w1, fb1,
                nullptr, uHi, uLo, nullptr, 2048, 2048, 8192, 2048);
            zacc_kernel<1><<<2048, blk, 0, stream>>>(uHi, uLo, v2, zc2, zb2 + roff, 8192);
            gemm_f32<1, 1, 0, 0, 0><<<dim3(16, 16), blk, 0, stream>>>(
                nullptr, uHi, w2, fb2, res2b, nullptr, nullptr, nullptr,
                8192, 8192, 2048, 8192);
            gate2_kernel<<<2048, blk, 0, stream>>>(
                dob + roff * 2048, res2b, zb2 + roff, u2 + roff, n2w, n2b);
        }
    }
}